// Round 14
// baseline (190.546 us; speedup 1.0000x reference)
//
#include <hip/hip_runtime.h>

typedef __attribute__((ext_vector_type(4))) float f32x4;
typedef __attribute__((ext_vector_type(8))) short s16x8;
typedef __attribute__((ext_vector_type(8))) unsigned short u16x8;
typedef __attribute__((address_space(1))) unsigned int g_uint;
typedef __attribute__((address_space(3))) unsigned int lds_uint;

#define T_LEN 2048
#define ENC_D 1024
#define ATT_D 512
#define CONV_C 10

static __device__ __forceinline__ unsigned short f2bf(float f) {
  unsigned int u = __float_as_uint(f);
  u += 0x7FFFu + ((u >> 16) & 1u);
  return (unsigned short)(u >> 16);
}

static __device__ __forceinline__ void gload16(const void* g, void* l) {
  __builtin_amdgcn_global_load_lds((const g_uint*)g, (lds_uint*)l, 16, 0, 0);
}

// ---------------- K0a: Wt2 tiles 0..31: tile(kt)[512 a][32 k] bf16, involution layout --------
// within-tile short offset: (a>>3)*256 + q*64 + ((a&7)^q)*8 + (k&7),  q=(k>>3)&3
__global__ void k_wt(const float* __restrict__ W, unsigned short* __restrict__ Wt2) {
  __shared__ float tile[64][65];
  int k0 = blockIdx.x * 64, a0 = blockIdx.y * 64;
  int tid = threadIdx.x;
  int r = tid >> 2, cg = tid & 3;
  #pragma unroll
  for (int i = 0; i < 4; ++i) {
    f32x4 v = *reinterpret_cast<const f32x4*>(&W[(size_t)(k0 + r) * ATT_D + a0 + cg * 16 + i * 4]);
    tile[r][cg * 16 + i * 4 + 0] = v[0];
    tile[r][cg * 16 + i * 4 + 1] = v[1];
    tile[r][cg * 16 + i * 4 + 2] = v[2];
    tile[r][cg * 16 + i * 4 + 3] = v[3];
  }
  __syncthreads();
  int r2 = tid >> 2, kg = tid & 3;
  u16x8 o0, o1;
  #pragma unroll
  for (int j = 0; j < 8; ++j) o0[j] = f2bf(tile[kg * 16 + j][r2]);
  #pragma unroll
  for (int j = 0; j < 8; ++j) o1[j] = f2bf(tile[kg * 16 + 8 + j][r2]);
  int a = a0 + r2;            // 0..511
  int k = k0 + kg * 16;       // 16-aligned
  int kt = k >> 5;
  int q0 = (k >> 3) & 3;      // 0 or 2
  size_t tb = (size_t)kt * 16384 + (a >> 3) * 256;
  int s7 = a & 7;
  *reinterpret_cast<u16x8*>(&Wt2[tb + q0 * 64 + (s7 ^ q0) * 8]) = o0;
  *reinterpret_cast<u16x8*>(&Wt2[tb + (q0 + 1) * 64 + (s7 ^ (q0 + 1)) * 8]) = o1;
}

// ---------------- K0a': tile 32 = W_att padded c->32, same layout ----------------
__global__ void k_watt(const float* __restrict__ Wa, unsigned short* __restrict__ Wt2) {
  int a = blockIdx.x * 256 + threadIdx.x;   // 0..511
  size_t tb = (size_t)32 * 16384 + (a >> 3) * 256;
  int s7 = a & 7;
  #pragma unroll
  for (int q2 = 0; q2 < 4; ++q2) {
    u16x8 v;
    #pragma unroll
    for (int j = 0; j < 8; ++j) {
      int c = q2 * 8 + j;
      v[j] = (c < CONV_C) ? f2bf(Wa[a * CONV_C + c]) : (unsigned short)0;
    }
    *reinterpret_cast<u16x8*>(&Wt2[tb + q2 * 64 + (s7 ^ q2) * 8]) = v;
  }
}

// ---------------- K0b: f_out[n][c][t] = conv129(ali_prev) + F_b  (R10 version) --------------
__global__ void k_conv(const float* __restrict__ ali, const float* __restrict__ Fw,
                       const float* __restrict__ Fb, float* __restrict__ fout) {
  int b = blockIdx.x;
  int tb = b & 7, nc = b >> 3;
  int c = nc % CONV_C, n = nc / CONV_C;
  __shared__ float sa[384];
  __shared__ float sw[129];
  int tid = threadIdx.x;
  int t0 = tb * 256;
  for (int i = tid; i < 384; i += 256) {
    int t = t0 - 64 + i;
    sa[i] = (t >= 0 && t < T_LEN) ? ali[n * T_LEN + t] : 0.f;
  }
  if (tid < 129) sw[tid] = Fw[c * 129 + tid];
  __syncthreads();
  float acc = Fb[c];
  #pragma unroll 8
  for (int k = 0; k < 129; ++k) acc += sw[k] * sa[tid + k];
  fout[(size_t)(n * CONV_C + c) * T_LEN + t0 + tid] = acc;
}

// ---------------- K0c: dec_ws[n][a] = dec_prev[n]@W_dec[:,a] + b_enc[a]  (512 blocks) ------
__global__ void k_dec(const float* __restrict__ dec_prev, const float* __restrict__ Wd,
                      const float* __restrict__ benc, float* __restrict__ dec_ws) {
  __shared__ float red[256];
  int b = blockIdx.x;
  int n = b >> 4, ac = b & 15;
  int tid = threadIdx.x;
  int dg = tid >> 5, al = tid & 31;
  int a = ac * 32 + al;
  const float* dp = dec_prev + (size_t)n * 1024 + dg * 128;
  const float* wp = Wd + (size_t)(dg * 128) * ATT_D + a;
  float s = 0.f;
  #pragma unroll 4
  for (int i = 0; i < 128; ++i) s += dp[i] * wp[(size_t)i * ATT_D];
  red[tid] = s;
  __syncthreads();
  if (dg == 0) {
    float t = benc[a];
    #pragma unroll
    for (int g = 0; g < 8; ++g) t += red[g * 32 + al];
    dec_ws[(size_t)n * ATT_D + a] = t;
  }
}

// ---------------- K1: fused score GEMM (BM=64, BN=512, BK=32, 4 waves, 2 blocks/CU) --------
// 72 KB LDS -> 2 independent blocks per CU: cross-block overlap hides barrier/drain latency
// (m114 mechanism). All layouts identical to proven R9/R10 rounds.
__global__ __launch_bounds__(256, 2) void k_score(
    const float* __restrict__ enc, const unsigned short* __restrict__ Wt2,
    const float* __restrict__ fout, const float* __restrict__ dec_ws,
    const float* __restrict__ w_vec, const int* __restrict__ enc_len,
    float* __restrict__ score_ws) {
  __shared__ __align__(16) char smem[73728];   // 2 x (B 32768 + A 4096)

  int bid = blockIdx.x;            // 1024 blocks: 32 n x 32 t-tiles of 64 rows
  int n, tt;
  if (bid < 512) { n = bid >> 4; tt = bid & 15; }          // always active (t < 1024)
  else { int p = bid - 512; n = p >> 4; tt = 16 + (p & 15); }
  int t0b = tt * 64;
  if (t0b >= enc_len[n]) return;   // fully-masked tile

  int tid = threadIdx.x;
  int wn = tid >> 6, lane = tid & 63;   // 4 waves over N
  int l15 = lane & 15, q = lane >> 4;

  const float* Ab = enc + ((size_t)n * T_LEN + t0b) * ENC_D;
  int arow = tid >> 2, aq = tid & 3;    // A row 0..63, 8-f32 chunk
  const float* Asrc = Ab + (size_t)arow * ENC_D + aq * 8;

  // involution offsets (bytes); B in buf[0..32768), A in buf[32768..36864)
  int awoff = 32768 + (arow >> 3) * 512 + aq * 128 + ((arow & 7) ^ aq) * 16;
  int swl = (l15 & 7) ^ q;
  int aql = 32768 + (l15 >> 3) * 512 + q * 128 + swl * 16;        // + m*1024
  int bql = (wn * 16 + (l15 >> 3)) * 512 + q * 128 + swl * 16;    // + nf*1024

  char* b0 = smem;
  char* b1 = smem + 36864;

  f32x4 acc[4][8];
  #pragma unroll
  for (int m = 0; m < 4; ++m)
    #pragma unroll
    for (int nf = 0; nf < 8; ++nf)
      acc[m][nf] = (f32x4){0.f, 0.f, 0.f, 0.f};

  f32x4 xA0, xA1;

  auto STAGE = [&](int kt, char* buf) {
    const float* pA = Asrc + (size_t)kt * 32;
    xA0 = *reinterpret_cast<const f32x4*>(pA);
    xA1 = *reinterpret_cast<const f32x4*>(pA + 4);
    const unsigned short* s = Wt2 + (size_t)kt * 16384 + tid * 8;
    #pragma unroll
    for (int i = 0; i < 8; ++i)
      gload16(s + i * 2048, buf + tid * 16 + i * 4096);
  };
  auto WRITEA = [&](char* buf) {
    union { u16x8 v; unsigned int u[4]; } pk;
    asm("v_cvt_pk_bf16_f32 %0, %1, %2" : "=v"(pk.u[0]) : "v"(xA0[0]), "v"(xA0[1]));
    asm("v_cvt_pk_bf16_f32 %0, %1, %2" : "=v"(pk.u[1]) : "v"(xA0[2]), "v"(xA0[3]));
    asm("v_cvt_pk_bf16_f32 %0, %1, %2" : "=v"(pk.u[2]) : "v"(xA1[0]), "v"(xA1[1]));
    asm("v_cvt_pk_bf16_f32 %0, %1, %2" : "=v"(pk.u[3]) : "v"(xA1[2]), "v"(xA1[3]));
    *reinterpret_cast<u16x8*>(buf + awoff) = pk.v;
  };
  auto compute = [&](const char* buf) {
    s16x8 af[4];
    #pragma unroll
    for (int m = 0; m < 4; ++m)
      af[m] = *reinterpret_cast<const s16x8*>(buf + aql + m * 1024);
    __builtin_amdgcn_s_setprio(1);
    #pragma unroll
    for (int nf = 0; nf < 8; ++nf) {
      s16x8 bf = *reinterpret_cast<const s16x8*>(buf + bql + nf * 1024);
      #pragma unroll
      for (int m = 0; m < 4; ++m)
        acc[m][nf] = __builtin_amdgcn_mfma_f32_16x16x32_bf16(af[m], bf, acc[m][nf], 0, 0, 0);
    }
    __builtin_amdgcn_s_setprio(0);
  };

  // ---- prologue: att tile (f-values + W_att) into b0, k=0 into b1 ----
  if (tid < 64) {                  // f tile: [64 t][32 c] bf16, c >= 10 zero
    float fv[CONV_C];
    #pragma unroll
    for (int c = 0; c < CONV_C; ++c)
      fv[c] = fout[((size_t)n * CONV_C + c) * T_LEN + t0b + tid];
    char* base = b0 + 32768 + (tid >> 3) * 512;
    int s7 = tid & 7;
    #pragma unroll
    for (int q2 = 0; q2 < 4; ++q2) {
      u16x8 v;
      #pragma unroll
      for (int e = 0; e < 8; ++e) {
        int c = q2 * 8 + e;
        v[e] = (c < CONV_C) ? f2bf(fv[c]) : (unsigned short)0;
      }
      *reinterpret_cast<u16x8*>(base + q2 * 128 + (s7 ^ q2) * 16) = v;
    }
  }
  {
    const unsigned short* s = Wt2 + (size_t)32 * 16384 + tid * 8;
    #pragma unroll
    for (int i = 0; i < 8; ++i)
      gload16(s + i * 2048, b0 + tid * 16 + i * 4096);
  }
  STAGE(0, b1);
  asm volatile("s_waitcnt vmcnt(0) lgkmcnt(0)" ::: "memory");
  __builtin_amdgcn_sched_barrier(0);
  __builtin_amdgcn_s_barrier();
  compute(b0);                     // att_part
  WRITEA(b1);                      // A(0)

  char* B2[2] = {b1, b0};
  for (int k = 0; k < 32; ++k) {
    asm volatile("s_waitcnt vmcnt(0) lgkmcnt(0)" ::: "memory");
    __builtin_amdgcn_sched_barrier(0);
    __builtin_amdgcn_s_barrier();
    if (k + 1 < 32) STAGE(k + 1, B2[(k + 1) & 1]);
    compute(B2[k & 1]);
    if (k + 1 < 32) WRITEA(B2[(k + 1) & 1]);
  }
  __syncthreads();

  // ---- epilogue: + dec, tanh, dot(w), row-reduce ----
  float* d_lds = (float*)smem;               // [512]
  float* w_lds = (float*)(smem + 2048);      // [512]
  float* red   = (float*)(smem + 4096);      // [4][64]
  d_lds[tid] = dec_ws[(size_t)n * ATT_D + tid];
  d_lds[tid + 256] = dec_ws[(size_t)n * ATT_D + tid + 256];
  w_lds[tid] = w_vec[tid];
  w_lds[tid + 256] = w_vec[tid + 256];
  __syncthreads();

  #pragma unroll
  for (int m = 0; m < 4; ++m) {
    #pragma unroll
    for (int j = 0; j < 4; ++j) {
      int row = m * 16 + q * 4 + j;
      float s = 0.f;
      #pragma unroll
      for (int nf = 0; nf < 8; ++nf) {
        int cl = wn * 128 + nf * 16 + l15;
        float x = acc[m][nf][j] + d_lds[cl];
        float e = __expf(2.f * x);
        float th = 1.f - 2.f / (e + 1.f);
        s += w_lds[cl] * th;
      }
      float v = s;
      v += __shfl_xor(v, 1);
      v += __shfl_xor(v, 2);
      v += __shfl_xor(v, 4);
      v += __shfl_xor(v, 8);
      if (l15 == 0) red[wn * 64 + row] = v;
    }
  }
  __syncthreads();
  if (tid < 64) {
    float s = red[tid] + red[64 + tid] + red[128 + tid] + red[192 + tid];
    score_ws[(size_t)n * T_LEN + t0b + tid] = s;
  }
}

// ---------------- K2: masked softmax over T per row ----------------
__global__ void k_softmax(const float* __restrict__ score_ws, const int* __restrict__ enc_len,
                          float* __restrict__ ali_out) {
  __shared__ float wmx[4], wsum[4];
  int n = blockIdx.x, tid = threadIdx.x;
  int len = enc_len[n];
  int w = tid >> 6, lane = tid & 63;
  float s[8], e[8];
  float mx = -1e30f;
  #pragma unroll
  for (int i = 0; i < 8; ++i) {
    int t = i * 256 + tid;
    float v = score_ws[n * T_LEN + t];
    s[i] = v;
    if (t < len) mx = fmaxf(mx, v);
  }
  #pragma unroll
  for (int off = 32; off; off >>= 1) mx = fmaxf(mx, __shfl_xor(mx, off));
  if (lane == 0) wmx[w] = mx;
  __syncthreads();
  mx = fmaxf(fmaxf(wmx[0], wmx[1]), fmaxf(wmx[2], wmx[3]));
  float sum = 0.f;
  #pragma unroll
  for (int i = 0; i < 8; ++i) {
    int t = i * 256 + tid;
    float v = (t < len) ? __expf(s[i] - mx) : 0.f;
    e[i] = v;
    sum += v;
  }
  #pragma unroll
  for (int off = 32; off; off >>= 1) sum += __shfl_xor(sum, off);
  if (lane == 0) wsum[w] = sum;
  __syncthreads();
  sum = wsum[0] + wsum[1] + wsum[2] + wsum[3];
  float inv = 1.f / sum;
  #pragma unroll
  for (int i = 0; i < 8; ++i) ali_out[n * T_LEN + i * 256 + tid] = e[i] * inv;
}

// ---------------- K3: ctx partials over T-chunks (skip masked chunks) ----------------
__global__ void k_ctx(const float* __restrict__ ali, const float* __restrict__ enc,
                      const int* __restrict__ enc_len, float* __restrict__ part) {
  int b = blockIdx.x;                   // n*32 + tc
  int n = b >> 5, tc = b & 31;
  int tid = threadIdx.x;
  if (tc * 64 >= enc_len[n]) {
    *reinterpret_cast<f32x4*>(&part[(size_t)b * ENC_D + tid * 4]) = (f32x4){0.f, 0.f, 0.f, 0.f};
    return;
  }
  f32x4 acc = (f32x4){0.f, 0.f, 0.f, 0.f};
  const float* ep = enc + (size_t)(n * T_LEN + tc * 64) * ENC_D + tid * 4;
  const float* ap = ali + n * T_LEN + tc * 64;
  #pragma unroll 4
  for (int i = 0; i < 64; ++i) {
    float a = ap[i];
    f32x4 ev = *reinterpret_cast<const f32x4*>(ep + (size_t)i * ENC_D);
    acc += ev * a;
  }
  *reinterpret_cast<f32x4*>(&part[(size_t)b * ENC_D + tid * 4]) = acc;
}

// ---------------- K4: reduce ctx partials ----------------
__global__ void k_ctx_red(const float* __restrict__ part, float* __restrict__ ctx_out) {
  int g = blockIdx.x * 256 + threadIdx.x;
  int n = g >> 10, d = g & 1023;
  float s = 0.f;
  #pragma unroll 8
  for (int tc = 0; tc < 32; ++tc) s += part[(size_t)(n * 32 + tc) * ENC_D + d];
  ctx_out[g] = s;
}

extern "C" void kernel_launch(void* const* d_in, const int* in_sizes, int n_in,
                              void* d_out, int out_size, void* d_ws, size_t ws_size,
                              hipStream_t stream) {
  const float* enc      = (const float*)d_in[0];
  const int*   enc_len  = (const int*)d_in[1];
  const float* dec_prev = (const float*)d_in[2];
  const float* ali_prev = (const float*)d_in[3];
  const float* W_enc    = (const float*)d_in[4];
  const float* b_enc    = (const float*)d_in[5];
  const float* W_dec    = (const float*)d_in[6];
  const float* F_w      = (const float*)d_in[7];
  const float* F_b      = (const float*)d_in[8];
  const float* W_att    = (const float*)d_in[9];
  const float* w_vec    = (const float*)d_in[10];
  float* out = (float*)d_out;

  char* ws = (char*)d_ws;
  unsigned short* Wt2 = (unsigned short*)ws;       // 33 x 32768 B = 1,081,344
  float* fout   = (float*)(ws + 1081344);          // 2,621,440 B
  float* dec_ws = (float*)(ws + 3702784);          //    65,536 B
  float* score  = (float*)(ws + 3768320);          //   262,144 B
  float* part   = (float*)(ws + 4030464);          // 4,194,304 B -> ends 8,224,768

  hipLaunchKernelGGL(k_wt, dim3(16, 8), dim3(256), 0, stream, W_enc, Wt2);
  hipLaunchKernelGGL(k_watt, dim3(2), dim3(256), 0, stream, W_att, Wt2);
  hipLaunchKernelGGL(k_conv, dim3(2560), dim3(256), 0, stream, ali_prev, F_w, F_b, fout);
  hipLaunchKernelGGL(k_dec, dim3(512), dim3(256), 0, stream, dec_prev, W_dec, b_enc, dec_ws);
  hipLaunchKernelGGL(k_score, dim3(1024), dim3(256), 0, stream, enc, Wt2, fout, dec_ws, w_vec, enc_len, score);
  hipLaunchKernelGGL(k_softmax, dim3(32), dim3(256), 0, stream, score, enc_len, out);
  hipLaunchKernelGGL(k_ctx, dim3(1024), dim3(256), 0, stream, out, enc, enc_len, part);
  hipLaunchKernelGGL(k_ctx_red, dim3(128), dim3(256), 0, stream, part, out + 65536);
}

// Round 15
// 162.308 us; speedup vs baseline: 1.1740x; 1.1740x over previous
//
#include <hip/hip_runtime.h>

typedef __attribute__((ext_vector_type(4))) float f32x4;
typedef __attribute__((ext_vector_type(8))) short s16x8;
typedef __attribute__((ext_vector_type(8))) unsigned short u16x8;
typedef __attribute__((address_space(1))) unsigned int g_uint;
typedef __attribute__((address_space(3))) unsigned int lds_uint;

#define T_LEN 2048
#define ENC_D 1024
#define ATT_D 512
#define CONV_C 10

static __device__ __forceinline__ unsigned short f2bf(float f) {
  unsigned int u = __float_as_uint(f);
  u += 0x7FFFu + ((u >> 16) & 1u);
  return (unsigned short)(u >> 16);
}

static __device__ __forceinline__ void gload16(const void* g, void* l) {
  __builtin_amdgcn_global_load_lds((const g_uint*)g, (lds_uint*)l, 16, 0, 0);
}

// ---------------- K0a: Wt2 tiles 0..15: tile(kt)[512 a][64 k] bf16, involution layout -------
// within-tile short offset: (a>>3)*512 + q*64 + ((a&7)^q)*8 + (k&7),  q=(k>>3)&7
__global__ void k_wt(const float* __restrict__ W, unsigned short* __restrict__ Wt2) {
  __shared__ float tile[64][65];
  int k0 = blockIdx.x * 64, a0 = blockIdx.y * 64;   // kt = blockIdx.x
  int tid = threadIdx.x;
  int r = tid >> 2, cg = tid & 3;
  #pragma unroll
  for (int i = 0; i < 4; ++i) {
    f32x4 v = *reinterpret_cast<const f32x4*>(&W[(size_t)(k0 + r) * ATT_D + a0 + cg * 16 + i * 4]);
    tile[r][cg * 16 + i * 4 + 0] = v[0];
    tile[r][cg * 16 + i * 4 + 1] = v[1];
    tile[r][cg * 16 + i * 4 + 2] = v[2];
    tile[r][cg * 16 + i * 4 + 3] = v[3];
  }
  __syncthreads();
  int r2 = tid >> 2, kg = tid & 3;
  u16x8 o0, o1;
  #pragma unroll
  for (int j = 0; j < 8; ++j) o0[j] = f2bf(tile[kg * 16 + j][r2]);
  #pragma unroll
  for (int j = 0; j < 8; ++j) o1[j] = f2bf(tile[kg * 16 + 8 + j][r2]);
  int a = a0 + r2;            // 0..511
  int kt = blockIdx.x;
  int q0 = kg * 2, q1 = q0 + 1;
  size_t tb = (size_t)kt * 32768 + (a >> 3) * 512;
  int s7 = a & 7;
  *reinterpret_cast<u16x8*>(&Wt2[tb + q0 * 64 + (s7 ^ q0) * 8]) = o0;
  *reinterpret_cast<u16x8*>(&Wt2[tb + q1 * 64 + (s7 ^ q1) * 8]) = o1;
}

// ---------------- K0a': tile 16 = W_att padded c->64, same layout ----------------
__global__ void k_watt(const float* __restrict__ Wa, unsigned short* __restrict__ Wt2) {
  int a = blockIdx.x * 256 + threadIdx.x;   // 0..511
  size_t tb = (size_t)16 * 32768 + (a >> 3) * 512;
  int s7 = a & 7;
  #pragma unroll
  for (int j = 0; j < 8; ++j) {
    u16x8 v;
    #pragma unroll
    for (int e = 0; e < 8; ++e) {
      int c = j * 8 + e;
      v[e] = (c < CONV_C) ? f2bf(Wa[a * CONV_C + c]) : (unsigned short)0;
    }
    *reinterpret_cast<u16x8*>(&Wt2[tb + j * 64 + (s7 ^ j) * 8]) = v;
  }
}

// ---------------- K0b: f_out[n][c][t] = conv129(ali_prev) + F_b ----------------
__global__ void k_conv(const float* __restrict__ ali, const float* __restrict__ Fw,
                       const float* __restrict__ Fb, float* __restrict__ fout) {
  int b = blockIdx.x;
  int tb = b & 7, nc = b >> 3;
  int c = nc % CONV_C, n = nc / CONV_C;
  __shared__ float sa[384];
  __shared__ float sw[129];
  int tid = threadIdx.x;
  int t0 = tb * 256;
  for (int i = tid; i < 384; i += 256) {
    int t = t0 - 64 + i;
    sa[i] = (t >= 0 && t < T_LEN) ? ali[n * T_LEN + t] : 0.f;
  }
  if (tid < 129) sw[tid] = Fw[c * 129 + tid];
  __syncthreads();
  float acc = Fb[c];
  #pragma unroll 8
  for (int k = 0; k < 129; ++k) acc += sw[k] * sa[tid + k];
  fout[(size_t)(n * CONV_C + c) * T_LEN + t0 + tid] = acc;
}

// ---------------- K0c: dec_ws[n][a] = dec_prev[n]@W_dec[:,a] + b_enc[a]  (512 blocks) ------
__global__ void k_dec(const float* __restrict__ dec_prev, const float* __restrict__ Wd,
                      const float* __restrict__ benc, float* __restrict__ dec_ws) {
  __shared__ float red[256];
  int b = blockIdx.x;
  int n = b >> 4, ac = b & 15;
  int tid = threadIdx.x;
  int dg = tid >> 5, al = tid & 31;
  int a = ac * 32 + al;
  const float* dp = dec_prev + (size_t)n * 1024 + dg * 128;
  const float* wp = Wd + (size_t)(dg * 128) * ATT_D + a;
  float s = 0.f;
  #pragma unroll 4
  for (int i = 0; i < 128; ++i) s += dp[i] * wp[(size_t)i * ATT_D];
  red[tid] = s;
  __syncthreads();
  if (dg == 0) {
    float t = benc[a];
    #pragma unroll
    for (int g = 0; g < 8; ++g) t += red[g * 32 + al];
    dec_ws[(size_t)n * ATT_D + a] = t;
  }
}

// ---------------- K1: fused score GEMM (BM=128, BN=512, BK=64, 8 waves, 2-buffer) ----------
__global__ __launch_bounds__(512, 2) void k_score(
    const float* __restrict__ enc, const unsigned short* __restrict__ Wt2,
    const float* __restrict__ fout, const float* __restrict__ dec_ws,
    const float* __restrict__ w_vec, const int* __restrict__ enc_len,
    float* __restrict__ score_ws) {
  __shared__ __align__(16) char smem[163840];   // 2 x (B 65536 + A 16384)

  int bid = blockIdx.x;            // 512 blocks, paired mapping for balance
  int half = bid >> 8, p = bid & 255;
  int n = p >> 3, i0 = p & 7;
  int tt = half ? (15 - i0) : i0;
  int t0b = tt * 128;
  if (t0b >= enc_len[n]) return;   // fully-masked tile

  int tid = threadIdx.x;
  int w = tid >> 6, lane = tid & 63;
  int l15 = lane & 15, q = lane >> 4;
  int wm = w >> 2, wn = w & 3;     // 2(M) x 4(N); wave tile 64 x 128

  const float* Ab = enc + ((size_t)n * T_LEN + t0b) * ENC_D;
  int arow = tid >> 2, aq4 = tid & 3;          // A row 0..127, 16-f32 span
  const float* Asrc = Ab + (size_t)arow * ENC_D + aq4 * 16;
  int c0 = aq4 * 2, c1 = c0 + 1;
  int awoff0 = 65536 + (arow >> 3) * 1024 + c0 * 128 + ((arow & 7) ^ c0) * 16;
  int awoff1 = 65536 + (arow >> 3) * 1024 + c1 * 128 + ((arow & 7) ^ c1) * 16;

  // fragment-read offsets (bytes)
  int x0 = (l15 & 7) ^ q;
  int ck0 = q * 128 + x0 * 16;                 // kk=0 chunk q
  int ck1 = 512 + q * 128 + (x0 ^ 4) * 16;     // kk=1 chunk 4+q
  int rgA = wm * 8 + (l15 >> 3);
  int rgB = wn * 16 + (l15 >> 3);

  char* b0 = smem;
  char* b1 = smem + 81920;

  f32x4 acc[4][8];
  #pragma unroll
  for (int m = 0; m < 4; ++m)
    #pragma unroll
    for (int nf = 0; nf < 8; ++nf)
      acc[m][nf] = (f32x4){0.f, 0.f, 0.f, 0.f};

  f32x4 xA0, xA1, xA2, xA3;

  auto STAGE = [&](int kt, char* buf) {
    const float* pA = Asrc + (size_t)kt * 64;
    xA0 = *reinterpret_cast<const f32x4*>(pA);
    xA1 = *reinterpret_cast<const f32x4*>(pA + 4);
    xA2 = *reinterpret_cast<const f32x4*>(pA + 8);
    xA3 = *reinterpret_cast<const f32x4*>(pA + 12);
    const unsigned short* s = Wt2 + (size_t)kt * 32768 + tid * 8;
    #pragma unroll
    for (int i = 0; i < 8; ++i)
      gload16(s + i * 4096, buf + tid * 16 + i * 8192);
  };
  auto WRITEA = [&](char* buf) {
    union { u16x8 v; unsigned int u[4]; } p0, p1;
    asm("v_cvt_pk_bf16_f32 %0, %1, %2" : "=v"(p0.u[0]) : "v"(xA0[0]), "v"(xA0[1]));
    asm("v_cvt_pk_bf16_f32 %0, %1, %2" : "=v"(p0.u[1]) : "v"(xA0[2]), "v"(xA0[3]));
    asm("v_cvt_pk_bf16_f32 %0, %1, %2" : "=v"(p0.u[2]) : "v"(xA1[0]), "v"(xA1[1]));
    asm("v_cvt_pk_bf16_f32 %0, %1, %2" : "=v"(p0.u[3]) : "v"(xA1[2]), "v"(xA1[3]));
    asm("v_cvt_pk_bf16_f32 %0, %1, %2" : "=v"(p1.u[0]) : "v"(xA2[0]), "v"(xA2[1]));
    asm("v_cvt_pk_bf16_f32 %0, %1, %2" : "=v"(p1.u[1]) : "v"(xA2[2]), "v"(xA2[3]));
    asm("v_cvt_pk_bf16_f32 %0, %1, %2" : "=v"(p1.u[2]) : "v"(xA3[0]), "v"(xA3[1]));
    asm("v_cvt_pk_bf16_f32 %0, %1, %2" : "=v"(p1.u[3]) : "v"(xA3[2]), "v"(xA3[3]));
    *reinterpret_cast<u16x8*>(buf + awoff0) = p0.v;
    *reinterpret_cast<u16x8*>(buf + awoff1) = p1.v;
  };
  auto compute = [&](const char* buf) {
    s16x8 af0[4], af1[4];
    #pragma unroll
    for (int m = 0; m < 4; ++m) {
      af0[m] = *reinterpret_cast<const s16x8*>(buf + 65536 + (rgA + m * 2) * 1024 + ck0);
      af1[m] = *reinterpret_cast<const s16x8*>(buf + 65536 + (rgA + m * 2) * 1024 + ck1);
    }
    __builtin_amdgcn_s_setprio(1);
    #pragma unroll
    for (int nf = 0; nf < 8; ++nf) {
      s16x8 bf0 = *reinterpret_cast<const s16x8*>(buf + (rgB + nf * 2) * 1024 + ck0);
      s16x8 bf1 = *reinterpret_cast<const s16x8*>(buf + (rgB + nf * 2) * 1024 + ck1);
      #pragma unroll
      for (int m = 0; m < 4; ++m) {
        acc[m][nf] = __builtin_amdgcn_mfma_f32_16x16x32_bf16(af0[m], bf0, acc[m][nf], 0, 0, 0);
        acc[m][nf] = __builtin_amdgcn_mfma_f32_16x16x32_bf16(af1[m], bf1, acc[m][nf], 0, 0, 0);
      }
    }
    __builtin_amdgcn_s_setprio(0);
  };

  // ---- prologue: att tile (f-values + W_att) into b0, k=0 into b1 ----
  if (tid < 128) {                 // f tile: [128 t][64 c] bf16, c >= 10 zero
    float fv[CONV_C];
    #pragma unroll
    for (int c = 0; c < CONV_C; ++c)
      fv[c] = fout[((size_t)n * CONV_C + c) * T_LEN + t0b + tid];
    char* base = b0 + 65536 + (tid >> 3) * 1024;
    int s7 = tid & 7;
    #pragma unroll
    for (int j = 0; j < 8; ++j) {
      u16x8 v;
      #pragma unroll
      for (int e = 0; e < 8; ++e) {
        int c = j * 8 + e;
        v[e] = (c < CONV_C) ? f2bf(fv[c]) : (unsigned short)0;
      }
      *reinterpret_cast<u16x8*>(base + j * 128 + (s7 ^ j) * 16) = v;
    }
  }
  {
    const unsigned short* s = Wt2 + (size_t)16 * 32768 + tid * 8;
    #pragma unroll
    for (int i = 0; i < 8; ++i)
      gload16(s + i * 4096, b0 + tid * 16 + i * 8192);
  }
  STAGE(0, b1);
  asm volatile("s_waitcnt vmcnt(0) lgkmcnt(0)" ::: "memory");
  __builtin_amdgcn_sched_barrier(0);
  __builtin_amdgcn_s_barrier();
  compute(b0);                     // att_part
  WRITEA(b1);                      // A(0)

  char* pc = b1; char* pn = b0;
  for (int k = 0; k < 16; ++k) {
    asm volatile("s_waitcnt vmcnt(0) lgkmcnt(0)" ::: "memory");
    __builtin_amdgcn_sched_barrier(0);
    __builtin_amdgcn_s_barrier();
    if (k + 1 < 16) STAGE(k + 1, pn);
    compute(pc);
    if (k + 1 < 16) WRITEA(pn);
    char* t = pc; pc = pn; pn = t;
  }
  __syncthreads();

  // ---- epilogue: + dec, tanh, dot(w), row-reduce ----
  float* d_lds = (float*)smem;               // [512]
  float* w_lds = (float*)(smem + 2048);      // [512]
  float* red   = (float*)(smem + 4096);      // [4][128]
  d_lds[tid] = dec_ws[(size_t)n * ATT_D + tid];
  w_lds[tid] = w_vec[tid];
  __syncthreads();

  #pragma unroll
  for (int m = 0; m < 4; ++m) {
    #pragma unroll
    for (int j = 0; j < 4; ++j) {
      int ttl = wm * 64 + m * 16 + q * 4 + j;
      float s = 0.f;
      #pragma unroll
      for (int nf = 0; nf < 8; ++nf) {
        int cl = wn * 128 + nf * 16 + l15;
        float x = acc[m][nf][j] + d_lds[cl];
        float e = __expf(2.f * x);
        float th = 1.f - 2.f / (e + 1.f);
        s += w_lds[cl] * th;
      }
      float v = s;
      v += __shfl_xor(v, 1);
      v += __shfl_xor(v, 2);
      v += __shfl_xor(v, 4);
      v += __shfl_xor(v, 8);
      if (l15 == 0) red[wn * 128 + ttl] = v;
    }
  }
  __syncthreads();
  if (tid < 128) {
    float s = red[tid] + red[128 + tid] + red[256 + tid] + red[384 + tid];
    score_ws[(size_t)n * T_LEN + t0b + tid] = s;
  }
}

// ---------------- K2: masked softmax over T per row ----------------
__global__ void k_softmax(const float* __restrict__ score_ws, const int* __restrict__ enc_len,
                          float* __restrict__ ali_out) {
  __shared__ float wmx[4], wsum[4];
  int n = blockIdx.x, tid = threadIdx.x;
  int len = enc_len[n];
  int w = tid >> 6, lane = tid & 63;
  float s[8], e[8];
  float mx = -1e30f;
  #pragma unroll
  for (int i = 0; i < 8; ++i) {
    int t = i * 256 + tid;
    float v = score_ws[n * T_LEN + t];
    s[i] = v;
    if (t < len) mx = fmaxf(mx, v);
  }
  #pragma unroll
  for (int off = 32; off; off >>= 1) mx = fmaxf(mx, __shfl_xor(mx, off));
  if (lane == 0) wmx[w] = mx;
  __syncthreads();
  mx = fmaxf(fmaxf(wmx[0], wmx[1]), fmaxf(wmx[2], wmx[3]));
  float sum = 0.f;
  #pragma unroll
  for (int i = 0; i < 8; ++i) {
    int t = i * 256 + tid;
    float v = (t < len) ? __expf(s[i] - mx) : 0.f;
    e[i] = v;
    sum += v;
  }
  #pragma unroll
  for (int off = 32; off; off >>= 1) sum += __shfl_xor(sum, off);
  if (lane == 0) wsum[w] = sum;
  __syncthreads();
  sum = wsum[0] + wsum[1] + wsum[2] + wsum[3];
  float inv = 1.f / sum;
  #pragma unroll
  for (int i = 0; i < 8; ++i) ali_out[n * T_LEN + i * 256 + tid] = e[i] * inv;
}

// ---------------- K3: ctx partials over T-chunks (skip masked chunks) ----------------
__global__ void k_ctx(const float* __restrict__ ali, const float* __restrict__ enc,
                      const int* __restrict__ enc_len, float* __restrict__ part) {
  int b = blockIdx.x;                   // n*32 + tc
  int n = b >> 5, tc = b & 31;
  int tid = threadIdx.x;
  if (tc * 64 >= enc_len[n]) {
    *reinterpret_cast<f32x4*>(&part[(size_t)b * ENC_D + tid * 4]) = (f32x4){0.f, 0.f, 0.f, 0.f};
    return;
  }
  f32x4 acc = (f32x4){0.f, 0.f, 0.f, 0.f};
  const float* ep = enc + (size_t)(n * T_LEN + tc * 64) * ENC_D + tid * 4;
  const float* ap = ali + n * T_LEN + tc * 64;
  #pragma unroll 4
  for (int i = 0; i < 64; ++i) {
    float a = ap[i];
    f32x4 ev = *reinterpret_cast<const f32x4*>(ep + (size_t)i * ENC_D);
    acc += ev * a;
  }
  *reinterpret_cast<f32x4*>(&part[(size_t)b * ENC_D + tid * 4]) = acc;
}

// ---------------- K4: reduce ctx partials ----------------
__global__ void k_ctx_red(const float* __restrict__ part, float* __restrict__ ctx_out) {
  int g = blockIdx.x * 256 + threadIdx.x;
  int n = g >> 10, d = g & 1023;
  float s = 0.f;
  #pragma unroll 8
  for (int tc = 0; tc < 32; ++tc) s += part[(size_t)(n * 32 + tc) * ENC_D + d];
  ctx_out[g] = s;
}

extern "C" void kernel_launch(void* const* d_in, const int* in_sizes, int n_in,
                              void* d_out, int out_size, void* d_ws, size_t ws_size,
                              hipStream_t stream) {
  const float* enc      = (const float*)d_in[0];
  const int*   enc_len  = (const int*)d_in[1];
  const float* dec_prev = (const float*)d_in[2];
  const float* ali_prev = (const float*)d_in[3];
  const float* W_enc    = (const float*)d_in[4];
  const float* b_enc    = (const float*)d_in[5];
  const float* W_dec    = (const float*)d_in[6];
  const float* F_w      = (const float*)d_in[7];
  const float* F_b      = (const float*)d_in[8];
  const float* W_att    = (const float*)d_in[9];
  const float* w_vec    = (const float*)d_in[10];
  float* out = (float*)d_out;

  char* ws = (char*)d_ws;
  unsigned short* Wt2 = (unsigned short*)ws;       // 17 x 65536 B = 1,114,112
  float* fout   = (float*)(ws + 1114112);          // 2,621,440 B
  float* dec_ws = (float*)(ws + 3735552);          //    65,536 B
  float* score  = (float*)(ws + 3801088);          //   262,144 B
  float* part   = (float*)(ws + 4063232);          // 4,194,304 B

  hipLaunchKernelGGL(k_wt, dim3(16, 8), dim3(256), 0, stream, W_enc, Wt2);
  hipLaunchKernelGGL(k_watt, dim3(2), dim3(256), 0, stream, W_att, Wt2);
  hipLaunchKernelGGL(k_conv, dim3(2560), dim3(256), 0, stream, ali_prev, F_w, F_b, fout);
  hipLaunchKernelGGL(k_dec, dim3(512), dim3(256), 0, stream, dec_prev, W_dec, b_enc, dec_ws);
  hipLaunchKernelGGL(k_score, dim3(512), dim3(512), 0, stream, enc, Wt2, fout, dec_ws, w_vec, enc_len, score);
  hipLaunchKernelGGL(k_softmax, dim3(32), dim3(256), 0, stream, score, enc_len, out);
  hipLaunchKernelGGL(k_ctx, dim3(1024), dim3(256), 0, stream, out, enc, enc_len, part);
  hipLaunchKernelGGL(k_ctx_red, dim3(128), dim3(256), 0, stream, part, out + 65536);
}

// Round 16
// 158.234 us; speedup vs baseline: 1.2042x; 1.0257x over previous
//
#include <hip/hip_runtime.h>

typedef __attribute__((ext_vector_type(4))) float f32x4;
typedef __attribute__((ext_vector_type(8))) short s16x8;
typedef __attribute__((ext_vector_type(8))) unsigned short u16x8;
typedef __attribute__((address_space(1))) unsigned int g_uint;
typedef __attribute__((address_space(3))) unsigned int lds_uint;

#define T_LEN 2048
#define ENC_D 1024
#define ATT_D 512
#define CONV_C 10

static __device__ __forceinline__ unsigned short f2bf(float f) {
  unsigned int u = __float_as_uint(f);
  u += 0x7FFFu + ((u >> 16) & 1u);
  return (unsigned short)(u >> 16);
}

static __device__ __forceinline__ void gload16(const void* g, void* l) {
  __builtin_amdgcn_global_load_lds((const g_uint*)g, (lds_uint*)l, 16, 0, 0);
}

// ---------------- K0: Wt2 prep (merged k_wt + k_watt), 130 blocks ----------------
// Blocks 0..127: tiles 0..15: tile(kt)[512 a][64 k] bf16, involution layout
//   within-tile short offset: (a>>3)*512 + q*64 + ((a&7)^q)*8 + (k&7),  q=(k>>3)&7
// Blocks 128..129: tile 16 = W_att padded c->64, same layout.
__global__ void k_prep(const float* __restrict__ W, const float* __restrict__ Wa,
                       unsigned short* __restrict__ Wt2) {
  int b = blockIdx.x;
  int tid = threadIdx.x;
  if (b < 128) {
    __shared__ float tile[64][65];
    int kt = b & 15, ab = b >> 4;
    int k0 = kt * 64, a0 = ab * 64;
    int r = tid >> 2, cg = tid & 3;
    #pragma unroll
    for (int i = 0; i < 4; ++i) {
      f32x4 v = *reinterpret_cast<const f32x4*>(&W[(size_t)(k0 + r) * ATT_D + a0 + cg * 16 + i * 4]);
      tile[r][cg * 16 + i * 4 + 0] = v[0];
      tile[r][cg * 16 + i * 4 + 1] = v[1];
      tile[r][cg * 16 + i * 4 + 2] = v[2];
      tile[r][cg * 16 + i * 4 + 3] = v[3];
    }
    __syncthreads();
    int r2 = tid >> 2, kg = tid & 3;
    u16x8 o0, o1;
    #pragma unroll
    for (int j = 0; j < 8; ++j) o0[j] = f2bf(tile[kg * 16 + j][r2]);
    #pragma unroll
    for (int j = 0; j < 8; ++j) o1[j] = f2bf(tile[kg * 16 + 8 + j][r2]);
    int a = a0 + r2;            // 0..511
    int q0 = kg * 2, q1 = q0 + 1;
    size_t tb = (size_t)kt * 32768 + (a >> 3) * 512;
    int s7 = a & 7;
    *reinterpret_cast<u16x8*>(&Wt2[tb + q0 * 64 + (s7 ^ q0) * 8]) = o0;
    *reinterpret_cast<u16x8*>(&Wt2[tb + q1 * 64 + (s7 ^ q1) * 8]) = o1;
  } else {
    int a = (b - 128) * 256 + tid;   // 0..511
    size_t tb = (size_t)16 * 32768 + (a >> 3) * 512;
    int s7 = a & 7;
    #pragma unroll
    for (int j = 0; j < 8; ++j) {
      u16x8 v;
      #pragma unroll
      for (int e = 0; e < 8; ++e) {
        int c = j * 8 + e;
        v[e] = (c < CONV_C) ? f2bf(Wa[a * CONV_C + c]) : (unsigned short)0;
      }
      *reinterpret_cast<u16x8*>(&Wt2[tb + j * 64 + (s7 ^ j) * 8]) = v;
    }
  }
}

// ---------------- K0b: f_out[n][c][t] = conv129(ali_prev) + F_b  (2 t per thread) ----------
__global__ void k_conv(const float* __restrict__ ali, const float* __restrict__ Fw,
                       const float* __restrict__ Fb, float* __restrict__ fout) {
  int b = blockIdx.x;              // 1280 = 32n x 10c x 4tb
  int tb = b & 3, nc = b >> 2;
  int c = nc % CONV_C, n = nc / CONV_C;
  __shared__ float sa[640];
  __shared__ float sw[129];
  int tid = threadIdx.x;
  int t0 = tb * 512;
  for (int i = tid; i < 640; i += 256) {
    int t = t0 - 64 + i;
    sa[i] = (t >= 0 && t < T_LEN) ? ali[n * T_LEN + t] : 0.f;
  }
  if (tid < 129) sw[tid] = Fw[c * 129 + tid];
  __syncthreads();
  float fb = Fb[c];
  float a0 = fb, a1 = fb;
  #pragma unroll 8
  for (int k = 0; k < 129; ++k) {
    float w = sw[k];
    a0 += w * sa[tid + k];
    a1 += w * sa[tid + 256 + k];
  }
  size_t base = (size_t)(n * CONV_C + c) * T_LEN + t0 + tid;
  fout[base] = a0;
  fout[base + 256] = a1;
}

// ---------------- K0c: dec_ws[n][a] = dec_prev[n]@W_dec[:,a] + b_enc[a]  (512 blocks) ------
__global__ void k_dec(const float* __restrict__ dec_prev, const float* __restrict__ Wd,
                      const float* __restrict__ benc, float* __restrict__ dec_ws) {
  __shared__ float red[256];
  int b = blockIdx.x;
  int n = b >> 4, ac = b & 15;
  int tid = threadIdx.x;
  int dg = tid >> 5, al = tid & 31;
  int a = ac * 32 + al;
  const float* dp = dec_prev + (size_t)n * 1024 + dg * 128;
  const float* wp = Wd + (size_t)(dg * 128) * ATT_D + a;
  float s = 0.f;
  #pragma unroll 4
  for (int i = 0; i < 128; ++i) s += dp[i] * wp[(size_t)i * ATT_D];
  red[tid] = s;
  __syncthreads();
  if (dg == 0) {
    float t = benc[a];
    #pragma unroll
    for (int g = 0; g < 8; ++g) t += red[g * 32 + al];
    dec_ws[(size_t)n * ATT_D + a] = t;
  }
}

// ---------------- K1: fused score GEMM (BM=128, BN=512, BK=64, 8 waves, 2-buffer) ----------
__global__ __launch_bounds__(512, 2) void k_score(
    const float* __restrict__ enc, const unsigned short* __restrict__ Wt2,
    const float* __restrict__ fout, const float* __restrict__ dec_ws,
    const float* __restrict__ w_vec, const int* __restrict__ enc_len,
    float* __restrict__ score_ws) {
  __shared__ __align__(16) char smem[163840];   // 2 x (B 65536 + A 16384)

  int bid = blockIdx.x;            // 512 blocks, paired mapping for balance
  int half = bid >> 8, p = bid & 255;
  int n = p >> 3, i0 = p & 7;
  int tt = half ? (15 - i0) : i0;
  int t0b = tt * 128;
  if (t0b >= enc_len[n]) return;   // fully-masked tile

  int tid = threadIdx.x;
  int w = tid >> 6, lane = tid & 63;
  int l15 = lane & 15, q = lane >> 4;
  int wm = w >> 2, wn = w & 3;     // 2(M) x 4(N); wave tile 64 x 128

  const float* Ab = enc + ((size_t)n * T_LEN + t0b) * ENC_D;
  int arow = tid >> 2, aq4 = tid & 3;          // A row 0..127, 16-f32 span
  const float* Asrc = Ab + (size_t)arow * ENC_D + aq4 * 16;
  int c0 = aq4 * 2, c1 = c0 + 1;
  int awoff0 = 65536 + (arow >> 3) * 1024 + c0 * 128 + ((arow & 7) ^ c0) * 16;
  int awoff1 = 65536 + (arow >> 3) * 1024 + c1 * 128 + ((arow & 7) ^ c1) * 16;

  // fragment-read offsets (bytes)
  int x0 = (l15 & 7) ^ q;
  int ck0 = q * 128 + x0 * 16;                 // kk=0 chunk q
  int ck1 = 512 + q * 128 + (x0 ^ 4) * 16;     // kk=1 chunk 4+q
  int rgA = wm * 8 + (l15 >> 3);
  int rgB = wn * 16 + (l15 >> 3);

  char* b0 = smem;
  char* b1 = smem + 81920;

  f32x4 acc[4][8];
  #pragma unroll
  for (int m = 0; m < 4; ++m)
    #pragma unroll
    for (int nf = 0; nf < 8; ++nf)
      acc[m][nf] = (f32x4){0.f, 0.f, 0.f, 0.f};

  f32x4 xA0, xA1, xA2, xA3;

  auto STAGE = [&](int kt, char* buf) {
    const float* pA = Asrc + (size_t)kt * 64;
    xA0 = *reinterpret_cast<const f32x4*>(pA);
    xA1 = *reinterpret_cast<const f32x4*>(pA + 4);
    xA2 = *reinterpret_cast<const f32x4*>(pA + 8);
    xA3 = *reinterpret_cast<const f32x4*>(pA + 12);
    const unsigned short* s = Wt2 + (size_t)kt * 32768 + tid * 8;
    #pragma unroll
    for (int i = 0; i < 8; ++i)
      gload16(s + i * 4096, buf + tid * 16 + i * 8192);
  };
  auto WRITEA = [&](char* buf) {
    union { u16x8 v; unsigned int u[4]; } p0, p1;
    asm("v_cvt_pk_bf16_f32 %0, %1, %2" : "=v"(p0.u[0]) : "v"(xA0[0]), "v"(xA0[1]));
    asm("v_cvt_pk_bf16_f32 %0, %1, %2" : "=v"(p0.u[1]) : "v"(xA0[2]), "v"(xA0[3]));
    asm("v_cvt_pk_bf16_f32 %0, %1, %2" : "=v"(p0.u[2]) : "v"(xA1[0]), "v"(xA1[1]));
    asm("v_cvt_pk_bf16_f32 %0, %1, %2" : "=v"(p0.u[3]) : "v"(xA1[2]), "v"(xA1[3]));
    asm("v_cvt_pk_bf16_f32 %0, %1, %2" : "=v"(p1.u[0]) : "v"(xA2[0]), "v"(xA2[1]));
    asm("v_cvt_pk_bf16_f32 %0, %1, %2" : "=v"(p1.u[1]) : "v"(xA2[2]), "v"(xA2[3]));
    asm("v_cvt_pk_bf16_f32 %0, %1, %2" : "=v"(p1.u[2]) : "v"(xA3[0]), "v"(xA3[1]));
    asm("v_cvt_pk_bf16_f32 %0, %1, %2" : "=v"(p1.u[3]) : "v"(xA3[2]), "v"(xA3[3]));
    *reinterpret_cast<u16x8*>(buf + awoff0) = p0.v;
    *reinterpret_cast<u16x8*>(buf + awoff1) = p1.v;
  };
  auto compute = [&](const char* buf) {
    s16x8 af0[4], af1[4];
    #pragma unroll
    for (int m = 0; m < 4; ++m) {
      af0[m] = *reinterpret_cast<const s16x8*>(buf + 65536 + (rgA + m * 2) * 1024 + ck0);
      af1[m] = *reinterpret_cast<const s16x8*>(buf + 65536 + (rgA + m * 2) * 1024 + ck1);
    }
    __builtin_amdgcn_s_setprio(1);
    #pragma unroll
    for (int nf = 0; nf < 8; ++nf) {
      s16x8 bf0 = *reinterpret_cast<const s16x8*>(buf + (rgB + nf * 2) * 1024 + ck0);
      s16x8 bf1 = *reinterpret_cast<const s16x8*>(buf + (rgB + nf * 2) * 1024 + ck1);
      #pragma unroll
      for (int m = 0; m < 4; ++m) {
        acc[m][nf] = __builtin_amdgcn_mfma_f32_16x16x32_bf16(af0[m], bf0, acc[m][nf], 0, 0, 0);
        acc[m][nf] = __builtin_amdgcn_mfma_f32_16x16x32_bf16(af1[m], bf1, acc[m][nf], 0, 0, 0);
      }
    }
    __builtin_amdgcn_s_setprio(0);
  };

  // ---- prologue: att tile (f-values + W_att) into b0, k=0 into b1 ----
  if (tid < 128) {                 // f tile: [128 t][64 c] bf16, c >= 10 zero
    float fv[CONV_C];
    #pragma unroll
    for (int c = 0; c < CONV_C; ++c)
      fv[c] = fout[((size_t)n * CONV_C + c) * T_LEN + t0b + tid];
    char* base = b0 + 65536 + (tid >> 3) * 1024;
    int s7 = tid & 7;
    #pragma unroll
    for (int j = 0; j < 8; ++j) {
      u16x8 v;
      #pragma unroll
      for (int e = 0; e < 8; ++e) {
        int c = j * 8 + e;
        v[e] = (c < CONV_C) ? f2bf(fv[c]) : (unsigned short)0;
      }
      *reinterpret_cast<u16x8*>(base + j * 128 + (s7 ^ j) * 16) = v;
    }
  }
  {
    const unsigned short* s = Wt2 + (size_t)16 * 32768 + tid * 8;
    #pragma unroll
    for (int i = 0; i < 8; ++i)
      gload16(s + i * 4096, b0 + tid * 16 + i * 8192);
  }
  STAGE(0, b1);
  asm volatile("s_waitcnt vmcnt(0) lgkmcnt(0)" ::: "memory");
  __builtin_amdgcn_sched_barrier(0);
  __builtin_amdgcn_s_barrier();
  compute(b0);                     // att_part
  WRITEA(b1);                      // A(0)

  char* pc = b1; char* pn = b0;
  for (int k = 0; k < 16; ++k) {
    asm volatile("s_waitcnt vmcnt(0) lgkmcnt(0)" ::: "memory");
    __builtin_amdgcn_sched_barrier(0);
    __builtin_amdgcn_s_barrier();
    if (k + 1 < 16) STAGE(k + 1, pn);
    compute(pc);
    if (k + 1 < 16) WRITEA(pn);
    char* t = pc; pc = pn; pn = t;
  }
  __syncthreads();

  // ---- epilogue: + dec, tanh, dot(w), row-reduce ----
  float* d_lds = (float*)smem;               // [512]
  float* w_lds = (float*)(smem + 2048);      // [512]
  float* red   = (float*)(smem + 4096);      // [4][128]
  d_lds[tid] = dec_ws[(size_t)n * ATT_D + tid];
  w_lds[tid] = w_vec[tid];
  __syncthreads();

  #pragma unroll
  for (int m = 0; m < 4; ++m) {
    #pragma unroll
    for (int j = 0; j < 4; ++j) {
      int ttl = wm * 64 + m * 16 + q * 4 + j;
      float s = 0.f;
      #pragma unroll
      for (int nf = 0; nf < 8; ++nf) {
        int cl = wn * 128 + nf * 16 + l15;
        float x = acc[m][nf][j] + d_lds[cl];
        float e = __expf(2.f * x);
        float th = 1.f - 2.f / (e + 1.f);
        s += w_lds[cl] * th;
      }
      float v = s;
      v += __shfl_xor(v, 1);
      v += __shfl_xor(v, 2);
      v += __shfl_xor(v, 4);
      v += __shfl_xor(v, 8);
      if (l15 == 0) red[wn * 128 + ttl] = v;
    }
  }
  __syncthreads();
  if (tid < 128) {
    float s = red[tid] + red[128 + tid] + red[256 + tid] + red[384 + tid];
    score_ws[(size_t)n * T_LEN + t0b + tid] = s;
  }
}

// ---------------- K2: masked softmax over T per row ----------------
__global__ void k_softmax(const float* __restrict__ score_ws, const int* __restrict__ enc_len,
                          float* __restrict__ ali_out) {
  __shared__ float wmx[4], wsum[4];
  int n = blockIdx.x, tid = threadIdx.x;
  int len = enc_len[n];
  int w = tid >> 6, lane = tid & 63;
  float s[8], e[8];
  float mx = -1e30f;
  #pragma unroll
  for (int i = 0; i < 8; ++i) {
    int t = i * 256 + tid;
    float v = score_ws[n * T_LEN + t];
    s[i] = v;
    if (t < len) mx = fmaxf(mx, v);
  }
  #pragma unroll
  for (int off = 32; off; off >>= 1) mx = fmaxf(mx, __shfl_xor(mx, off));
  if (lane == 0) wmx[w] = mx;
  __syncthreads();
  mx = fmaxf(fmaxf(wmx[0], wmx[1]), fmaxf(wmx[2], wmx[3]));
  float sum = 0.f;
  #pragma unroll
  for (int i = 0; i < 8; ++i) {
    int t = i * 256 + tid;
    float v = (t < len) ? __expf(s[i] - mx) : 0.f;
    e[i] = v;
    sum += v;
  }
  #pragma unroll
  for (int off = 32; off; off >>= 1) sum += __shfl_xor(sum, off);
  if (lane == 0) wsum[w] = sum;
  __syncthreads();
  sum = wsum[0] + wsum[1] + wsum[2] + wsum[3];
  float inv = 1.f / sum;
  #pragma unroll
  for (int i = 0; i < 8; ++i) ali_out[n * T_LEN + i * 256 + tid] = e[i] * inv;
}

// ---------------- K3: ctx partials over T-chunks (skip masked chunks) ----------------
__global__ void k_ctx(const float* __restrict__ ali, const float* __restrict__ enc,
                      const int* __restrict__ enc_len, float* __restrict__ part) {
  int b = blockIdx.x;                   // n*32 + tc
  int n = b >> 5, tc = b & 31;
  int tid = threadIdx.x;
  if (tc * 64 >= enc_len[n]) {
    *reinterpret_cast<f32x4*>(&part[(size_t)b * ENC_D + tid * 4]) = (f32x4){0.f, 0.f, 0.f, 0.f};
    return;
  }
  f32x4 acc = (f32x4){0.f, 0.f, 0.f, 0.f};
  const float* ep = enc + (size_t)(n * T_LEN + tc * 64) * ENC_D + tid * 4;
  const float* ap = ali + n * T_LEN + tc * 64;
  #pragma unroll 4
  for (int i = 0; i < 64; ++i) {
    float a = ap[i];
    f32x4 ev = *reinterpret_cast<const f32x4*>(ep + (size_t)i * ENC_D);
    acc += ev * a;
  }
  *reinterpret_cast<f32x4*>(&part[(size_t)b * ENC_D + tid * 4]) = acc;
}

// ---------------- K4: reduce ctx partials ----------------
__global__ void k_ctx_red(const float* __restrict__ part, float* __restrict__ ctx_out) {
  int g = blockIdx.x * 256 + threadIdx.x;
  int n = g >> 10, d = g & 1023;
  float s = 0.f;
  #pragma unroll 8
  for (int tc = 0; tc < 32; ++tc) s += part[(size_t)(n * 32 + tc) * ENC_D + d];
  ctx_out[g] = s;
}

extern "C" void kernel_launch(void* const* d_in, const int* in_sizes, int n_in,
                              void* d_out, int out_size, void* d_ws, size_t ws_size,
                              hipStream_t stream) {
  const float* enc      = (const float*)d_in[0];
  const int*   enc_len  = (const int*)d_in[1];
  const float* dec_prev = (const float*)d_in[2];
  const float* ali_prev = (const float*)d_in[3];
  const float* W_enc    = (const float*)d_in[4];
  const float* b_enc    = (const float*)d_in[5];
  const float* W_dec    = (const float*)d_in[6];
  const float* F_w      = (const float*)d_in[7];
  const float* F_b      = (const float*)d_in[8];
  const float* W_att    = (const float*)d_in[9];
  const float* w_vec    = (const float*)d_in[10];
  float* out = (float*)d_out;

  char* ws = (char*)d_ws;
  unsigned short* Wt2 = (unsigned short*)ws;       // 17 x 65536 B = 1,114,112
  float* fout   = (float*)(ws + 1114112);          // 2,621,440 B
  float* dec_ws = (float*)(ws + 3735552);          //    65,536 B
  float* score  = (float*)(ws + 3801088);          //   262,144 B
  float* part   = (float*)(ws + 4063232);          // 4,194,304 B

  hipLaunchKernelGGL(k_prep, dim3(130), dim3(256), 0, stream, W_enc, W_att, Wt2);
  hipLaunchKernelGGL(k_conv, dim3(1280), dim3(256), 0, stream, ali_prev, F_w, F_b, fout);
  hipLaunchKernelGGL(k_dec, dim3(512), dim3(256), 0, stream, dec_prev, W_dec, b_enc, dec_ws);
  hipLaunchKernelGGL(k_score, dim3(512), dim3(512), 0, stream, enc, Wt2, fout, dec_ws, w_vec, enc_len, score);
  hipLaunchKernelGGL(k_softmax, dim3(32), dim3(256), 0, stream, score, enc_len, out);
  hipLaunchKernelGGL(k_ctx, dim3(1024), dim3(256), 0, stream, out, enc, enc_len, part);
  hipLaunchKernelGGL(k_ctx_red, dim3(128), dim3(256), 0, stream, part, out + 65536);
}

// Round 17
// 150.106 us; speedup vs baseline: 1.2694x; 1.0542x over previous
//
#include <hip/hip_runtime.h>

typedef __attribute__((ext_vector_type(4))) float f32x4;
typedef __attribute__((ext_vector_type(8))) short s16x8;
typedef __attribute__((ext_vector_type(8))) unsigned short u16x8;
typedef __attribute__((address_space(1))) unsigned int g_uint;
typedef __attribute__((address_space(3))) unsigned int lds_uint;

#define T_LEN 2048
#define ENC_D 1024
#define ATT_D 512
#define CONV_C 10

static __device__ __forceinline__ unsigned short f2bf(float f) {
  unsigned int u = __float_as_uint(f);
  u += 0x7FFFu + ((u >> 16) & 1u);
  return (unsigned short)(u >> 16);
}

static __device__ __forceinline__ void gload16(const void* g, void* l) {
  __builtin_amdgcn_global_load_lds((const g_uint*)g, (lds_uint*)l, 16, 0, 0);
}

// ---------------- K0: fused prep (Wt2 pack + W_att pack + conv129 + dec proj) --------------
// Blocks 0..127   : Wt2 tiles 0..15: tile(kt)[512 a][64 k] bf16, involution layout
//                   within-tile short offset: (a>>3)*512 + q*64 + ((a&7)^q)*8 + (k&7), q=(k>>3)&7
// Blocks 128..129 : tile 16 = W_att padded c->64, same layout
// Blocks 130..1409: f_out[n][c][t] = conv129(ali_prev) + F_b  (2 t per thread)
// Blocks 1410..1921: dec_ws[n][a] = dec_prev[n]@W_dec[:,a] + b_enc[a]
// All three are independent; fusing removes two launch bubbles. Branches are
// block-uniform so per-branch __syncthreads is legal.
__global__ void k_pre(const float* __restrict__ W, const float* __restrict__ Wa,
                      unsigned short* __restrict__ Wt2,
                      const float* __restrict__ ali, const float* __restrict__ Fw,
                      const float* __restrict__ Fb, float* __restrict__ fout,
                      const float* __restrict__ dec_prev, const float* __restrict__ Wd,
                      const float* __restrict__ benc, float* __restrict__ dec_ws) {
  __shared__ __align__(16) char sh[16640];
  int b = blockIdx.x;
  int tid = threadIdx.x;
  if (b < 128) {
    float (*tile)[65] = (float(*)[65])sh;     // 64 x 65 x 4 = 16640 B
    int kt = b & 15, ab = b >> 4;
    int k0 = kt * 64, a0 = ab * 64;
    int r = tid >> 2, cg = tid & 3;
    #pragma unroll
    for (int i = 0; i < 4; ++i) {
      f32x4 v = *reinterpret_cast<const f32x4*>(&W[(size_t)(k0 + r) * ATT_D + a0 + cg * 16 + i * 4]);
      tile[r][cg * 16 + i * 4 + 0] = v[0];
      tile[r][cg * 16 + i * 4 + 1] = v[1];
      tile[r][cg * 16 + i * 4 + 2] = v[2];
      tile[r][cg * 16 + i * 4 + 3] = v[3];
    }
    __syncthreads();
    int r2 = tid >> 2, kg = tid & 3;
    u16x8 o0, o1;
    #pragma unroll
    for (int j = 0; j < 8; ++j) o0[j] = f2bf(tile[kg * 16 + j][r2]);
    #pragma unroll
    for (int j = 0; j < 8; ++j) o1[j] = f2bf(tile[kg * 16 + 8 + j][r2]);
    int a = a0 + r2;            // 0..511
    int q0 = kg * 2, q1 = q0 + 1;
    size_t tb = (size_t)kt * 32768 + (a >> 3) * 512;
    int s7 = a & 7;
    *reinterpret_cast<u16x8*>(&Wt2[tb + q0 * 64 + (s7 ^ q0) * 8]) = o0;
    *reinterpret_cast<u16x8*>(&Wt2[tb + q1 * 64 + (s7 ^ q1) * 8]) = o1;
  } else if (b < 130) {
    int a = (b - 128) * 256 + tid;   // 0..511
    size_t tb = (size_t)16 * 32768 + (a >> 3) * 512;
    int s7 = a & 7;
    #pragma unroll
    for (int j = 0; j < 8; ++j) {
      u16x8 v;
      #pragma unroll
      for (int e = 0; e < 8; ++e) {
        int c = j * 8 + e;
        v[e] = (c < CONV_C) ? f2bf(Wa[a * CONV_C + c]) : (unsigned short)0;
      }
      *reinterpret_cast<u16x8*>(&Wt2[tb + j * 64 + (s7 ^ j) * 8]) = v;
    }
  } else if (b < 1410) {
    int bb = b - 130;               // 1280 = 32n x 10c x 4tb
    float* sa = (float*)sh;         // [640]
    float* sw = (float*)(sh + 2560);// [129]
    int tb = bb & 3, nc = bb >> 2;
    int c = nc % CONV_C, n = nc / CONV_C;
    int t0 = tb * 512;
    for (int i = tid; i < 640; i += 256) {
      int t = t0 - 64 + i;
      sa[i] = (t >= 0 && t < T_LEN) ? ali[n * T_LEN + t] : 0.f;
    }
    if (tid < 129) sw[tid] = Fw[c * 129 + tid];
    __syncthreads();
    float fb = Fb[c];
    float a0 = fb, a1 = fb;
    #pragma unroll 8
    for (int k = 0; k < 129; ++k) {
      float w = sw[k];
      a0 += w * sa[tid + k];
      a1 += w * sa[tid + 256 + k];
    }
    size_t base = (size_t)(n * CONV_C + c) * T_LEN + t0 + tid;
    fout[base] = a0;
    fout[base + 256] = a1;
  } else {
    int bb = b - 1410;              // 512 = 32n x 16ac
    float* red = (float*)sh;        // [256]
    int n = bb >> 4, ac = bb & 15;
    int dg = tid >> 5, al = tid & 31;
    int a = ac * 32 + al;
    const float* dp = dec_prev + (size_t)n * 1024 + dg * 128;
    const float* wp = Wd + (size_t)(dg * 128) * ATT_D + a;
    float s = 0.f;
    #pragma unroll 4
    for (int i = 0; i < 128; ++i) s += dp[i] * wp[(size_t)i * ATT_D];
    red[tid] = s;
    __syncthreads();
    if (dg == 0) {
      float t = benc[a];
      #pragma unroll
      for (int g = 0; g < 8; ++g) t += red[g * 32 + al];
      dec_ws[(size_t)n * ATT_D + a] = t;
    }
  }
}

// ---------------- K1: fused score GEMM (BM=128, BN=512, BK=64, 8 waves, 2-buffer) ----------
__global__ __launch_bounds__(512, 2) void k_score(
    const float* __restrict__ enc, const unsigned short* __restrict__ Wt2,
    const float* __restrict__ fout, const float* __restrict__ dec_ws,
    const float* __restrict__ w_vec, const int* __restrict__ enc_len,
    float* __restrict__ score_ws) {
  __shared__ __align__(16) char smem[163840];   // 2 x (B 65536 + A 16384)

  int bid = blockIdx.x;            // 512 blocks, paired mapping for balance
  int half = bid >> 8, p = bid & 255;
  int n = p >> 3, i0 = p & 7;
  int tt = half ? (15 - i0) : i0;
  int t0b = tt * 128;
  if (t0b >= enc_len[n]) return;   // fully-masked tile

  int tid = threadIdx.x;
  int w = tid >> 6, lane = tid & 63;
  int l15 = lane & 15, q = lane >> 4;
  int wm = w >> 2, wn = w & 3;     // 2(M) x 4(N); wave tile 64 x 128

  const float* Ab = enc + ((size_t)n * T_LEN + t0b) * ENC_D;
  int arow = tid >> 2, aq4 = tid & 3;          // A row 0..127, 16-f32 span
  const float* Asrc = Ab + (size_t)arow * ENC_D + aq4 * 16;
  int c0 = aq4 * 2, c1 = c0 + 1;
  int awoff0 = 65536 + (arow >> 3) * 1024 + c0 * 128 + ((arow & 7) ^ c0) * 16;
  int awoff1 = 65536 + (arow >> 3) * 1024 + c1 * 128 + ((arow & 7) ^ c1) * 16;

  // fragment-read offsets (bytes)
  int x0 = (l15 & 7) ^ q;
  int ck0 = q * 128 + x0 * 16;                 // kk=0 chunk q
  int ck1 = 512 + q * 128 + (x0 ^ 4) * 16;     // kk=1 chunk 4+q
  int rgA = wm * 8 + (l15 >> 3);
  int rgB = wn * 16 + (l15 >> 3);

  char* b0 = smem;
  char* b1 = smem + 81920;

  f32x4 acc[4][8];
  #pragma unroll
  for (int m = 0; m < 4; ++m)
    #pragma unroll
    for (int nf = 0; nf < 8; ++nf)
      acc[m][nf] = (f32x4){0.f, 0.f, 0.f, 0.f};

  f32x4 xA0, xA1, xA2, xA3;

  auto STAGE = [&](int kt, char* buf) {
    const float* pA = Asrc + (size_t)kt * 64;
    xA0 = *reinterpret_cast<const f32x4*>(pA);
    xA1 = *reinterpret_cast<const f32x4*>(pA + 4);
    xA2 = *reinterpret_cast<const f32x4*>(pA + 8);
    xA3 = *reinterpret_cast<const f32x4*>(pA + 12);
    const unsigned short* s = Wt2 + (size_t)kt * 32768 + tid * 8;
    #pragma unroll
    for (int i = 0; i < 8; ++i)
      gload16(s + i * 4096, buf + tid * 16 + i * 8192);
  };
  auto WRITEA = [&](char* buf) {
    union { u16x8 v; unsigned int u[4]; } p0, p1;
    asm("v_cvt_pk_bf16_f32 %0, %1, %2" : "=v"(p0.u[0]) : "v"(xA0[0]), "v"(xA0[1]));
    asm("v_cvt_pk_bf16_f32 %0, %1, %2" : "=v"(p0.u[1]) : "v"(xA0[2]), "v"(xA0[3]));
    asm("v_cvt_pk_bf16_f32 %0, %1, %2" : "=v"(p0.u[2]) : "v"(xA1[0]), "v"(xA1[1]));
    asm("v_cvt_pk_bf16_f32 %0, %1, %2" : "=v"(p0.u[3]) : "v"(xA1[2]), "v"(xA1[3]));
    asm("v_cvt_pk_bf16_f32 %0, %1, %2" : "=v"(p1.u[0]) : "v"(xA2[0]), "v"(xA2[1]));
    asm("v_cvt_pk_bf16_f32 %0, %1, %2" : "=v"(p1.u[1]) : "v"(xA2[2]), "v"(xA2[3]));
    asm("v_cvt_pk_bf16_f32 %0, %1, %2" : "=v"(p1.u[2]) : "v"(xA3[0]), "v"(xA3[1]));
    asm("v_cvt_pk_bf16_f32 %0, %1, %2" : "=v"(p1.u[3]) : "v"(xA3[2]), "v"(xA3[3]));
    *reinterpret_cast<u16x8*>(buf + awoff0) = p0.v;
    *reinterpret_cast<u16x8*>(buf + awoff1) = p1.v;
  };
  auto compute = [&](const char* buf) {
    s16x8 af0[4], af1[4];
    #pragma unroll
    for (int m = 0; m < 4; ++m) {
      af0[m] = *reinterpret_cast<const s16x8*>(buf + 65536 + (rgA + m * 2) * 1024 + ck0);
      af1[m] = *reinterpret_cast<const s16x8*>(buf + 65536 + (rgA + m * 2) * 1024 + ck1);
    }
    __builtin_amdgcn_s_setprio(1);
    #pragma unroll
    for (int nf = 0; nf < 8; ++nf) {
      s16x8 bf0 = *reinterpret_cast<const s16x8*>(buf + (rgB + nf * 2) * 1024 + ck0);
      s16x8 bf1 = *reinterpret_cast<const s16x8*>(buf + (rgB + nf * 2) * 1024 + ck1);
      #pragma unroll
      for (int m = 0; m < 4; ++m) {
        acc[m][nf] = __builtin_amdgcn_mfma_f32_16x16x32_bf16(af0[m], bf0, acc[m][nf], 0, 0, 0);
        acc[m][nf] = __builtin_amdgcn_mfma_f32_16x16x32_bf16(af1[m], bf1, acc[m][nf], 0, 0, 0);
      }
    }
    __builtin_amdgcn_s_setprio(0);
  };

  // ---- prologue: att tile (f-values + W_att) into b0, k=0 into b1 ----
  if (tid < 128) {                 // f tile: [128 t][64 c] bf16, c >= 10 zero
    float fv[CONV_C];
    #pragma unroll
    for (int c = 0; c < CONV_C; ++c)
      fv[c] = fout[((size_t)n * CONV_C + c) * T_LEN + t0b + tid];
    char* base = b0 + 65536 + (tid >> 3) * 1024;
    int s7 = tid & 7;
    #pragma unroll
    for (int j = 0; j < 8; ++j) {
      u16x8 v;
      #pragma unroll
      for (int e = 0; e < 8; ++e) {
        int c = j * 8 + e;
        v[e] = (c < CONV_C) ? f2bf(fv[c]) : (unsigned short)0;
      }
      *reinterpret_cast<u16x8*>(base + j * 128 + (s7 ^ j) * 16) = v;
    }
  }
  {
    const unsigned short* s = Wt2 + (size_t)16 * 32768 + tid * 8;
    #pragma unroll
    for (int i = 0; i < 8; ++i)
      gload16(s + i * 4096, b0 + tid * 16 + i * 8192);
  }
  STAGE(0, b1);
  asm volatile("s_waitcnt vmcnt(0) lgkmcnt(0)" ::: "memory");
  __builtin_amdgcn_sched_barrier(0);
  __builtin_amdgcn_s_barrier();
  compute(b0);                     // att_part
  WRITEA(b1);                      // A(0)

  char* pc = b1; char* pn = b0;
  for (int k = 0; k < 16; ++k) {
    asm volatile("s_waitcnt vmcnt(0) lgkmcnt(0)" ::: "memory");
    __builtin_amdgcn_sched_barrier(0);
    __builtin_amdgcn_s_barrier();
    if (k + 1 < 16) STAGE(k + 1, pn);
    compute(pc);
    if (k + 1 < 16) WRITEA(pn);
    char* t = pc; pc = pn; pn = t;
  }
  __syncthreads();

  // ---- epilogue: + dec, tanh, dot(w), row-reduce ----
  float* d_lds = (float*)smem;               // [512]
  float* w_lds = (float*)(smem + 2048);      // [512]
  float* red   = (float*)(smem + 4096);      // [4][128]
  d_lds[tid] = dec_ws[(size_t)n * ATT_D + tid];
  w_lds[tid] = w_vec[tid];
  __syncthreads();

  #pragma unroll
  for (int m = 0; m < 4; ++m) {
    #pragma unroll
    for (int j = 0; j < 4; ++j) {
      int ttl = wm * 64 + m * 16 + q * 4 + j;
      float s = 0.f;
      #pragma unroll
      for (int nf = 0; nf < 8; ++nf) {
        int cl = wn * 128 + nf * 16 + l15;
        float x = acc[m][nf][j] + d_lds[cl];
        float e = __expf(2.f * x);
        float th = 1.f - 2.f / (e + 1.f);
        s += w_lds[cl] * th;
      }
      float v = s;
      v += __shfl_xor(v, 1);
      v += __shfl_xor(v, 2);
      v += __shfl_xor(v, 4);
      v += __shfl_xor(v, 8);
      if (l15 == 0) red[wn * 128 + ttl] = v;
    }
  }
  __syncthreads();
  if (tid < 128) {
    float s = red[tid] + red[128 + tid] + red[256 + tid] + red[384 + tid];
    score_ws[(size_t)n * T_LEN + t0b + tid] = s;
  }
}

// ---------------- K2: masked softmax over T per row ----------------
__global__ void k_softmax(const float* __restrict__ score_ws, const int* __restrict__ enc_len,
                          float* __restrict__ ali_out) {
  __shared__ float wmx[4], wsum[4];
  int n = blockIdx.x, tid = threadIdx.x;
  int len = enc_len[n];
  int w = tid >> 6, lane = tid & 63;
  float s[8], e[8];
  float mx = -1e30f;
  #pragma unroll
  for (int i = 0; i < 8; ++i) {
    int t = i * 256 + tid;
    float v = score_ws[n * T_LEN + t];
    s[i] = v;
    if (t < len) mx = fmaxf(mx, v);
  }
  #pragma unroll
  for (int off = 32; off; off >>= 1) mx = fmaxf(mx, __shfl_xor(mx, off));
  if (lane == 0) wmx[w] = mx;
  __syncthreads();
  mx = fmaxf(fmaxf(wmx[0], wmx[1]), fmaxf(wmx[2], wmx[3]));
  float sum = 0.f;
  #pragma unroll
  for (int i = 0; i < 8; ++i) {
    int t = i * 256 + tid;
    float v = (t < len) ? __expf(s[i] - mx) : 0.f;
    e[i] = v;
    sum += v;
  }
  #pragma unroll
  for (int off = 32; off; off >>= 1) sum += __shfl_xor(sum, off);
  if (lane == 0) wsum[w] = sum;
  __syncthreads();
  sum = wsum[0] + wsum[1] + wsum[2] + wsum[3];
  float inv = 1.f / sum;
  #pragma unroll
  for (int i = 0; i < 8; ++i) ali_out[n * T_LEN + i * 256 + tid] = e[i] * inv;
}

// ---------------- K3: ctx partials over T-chunks (skip masked chunks) ----------------
__global__ void k_ctx(const float* __restrict__ ali, const float* __restrict__ enc,
                      const int* __restrict__ enc_len, float* __restrict__ part) {
  int b = blockIdx.x;                   // n*32 + tc
  int n = b >> 5, tc = b & 31;
  int tid = threadIdx.x;
  if (tc * 64 >= enc_len[n]) {
    *reinterpret_cast<f32x4*>(&part[(size_t)b * ENC_D + tid * 4]) = (f32x4){0.f, 0.f, 0.f, 0.f};
    return;
  }
  f32x4 acc = (f32x4){0.f, 0.f, 0.f, 0.f};
  const float* ep = enc + (size_t)(n * T_LEN + tc * 64) * ENC_D + tid * 4;
  const float* ap = ali + n * T_LEN + tc * 64;
  #pragma unroll 4
  for (int i = 0; i < 64; ++i) {
    float a = ap[i];
    f32x4 ev = *reinterpret_cast<const f32x4*>(ep + (size_t)i * ENC_D);
    acc += ev * a;
  }
  *reinterpret_cast<f32x4*>(&part[(size_t)b * ENC_D + tid * 4]) = acc;
}

// ---------------- K4: reduce ctx partials ----------------
__global__ void k_ctx_red(const float* __restrict__ part, float* __restrict__ ctx_out) {
  int g = blockIdx.x * 256 + threadIdx.x;
  int n = g >> 10, d = g & 1023;
  float s = 0.f;
  #pragma unroll 8
  for (int tc = 0; tc < 32; ++tc) s += part[(size_t)(n * 32 + tc) * ENC_D + d];
  ctx_out[g] = s;
}

extern "C" void kernel_launch(void* const* d_in, const int* in_sizes, int n_in,
                              void* d_out, int out_size, void* d_ws, size_t ws_size,
                              hipStream_t stream) {
  const float* enc      = (const float*)d_in[0];
  const int*   enc_len  = (const int*)d_in[1];
  const float* dec_prev = (const float*)d_in[2];
  const float* ali_prev = (const float*)d_in[3];
  const float* W_enc    = (const float*)d_in[4];
  const float* b_enc    = (const float*)d_in[5];
  const float* W_dec    = (const float*)d_in[6];
  const float* F_w      = (const float*)d_in[7];
  const float* F_b      = (const float*)d_in[8];
  const float* W_att    = (const float*)d_in[9];
  const float* w_vec    = (const float*)d_in[10];
  float* out = (float*)d_out;

  char* ws = (char*)d_ws;
  unsigned short* Wt2 = (unsigned short*)ws;       // 17 x 65536 B = 1,114,112
  float* fout   = (float*)(ws + 1114112);          // 2,621,440 B
  float* dec_ws = (float*)(ws + 3735552);          //    65,536 B
  float* score  = (float*)(ws + 3801088);          //   262,144 B
  float* part   = (float*)(ws + 4063232);          // 4,194,304 B

  hipLaunchKernelGGL(k_pre, dim3(1922), dim3(256), 0, stream,
                     W_enc, W_att, Wt2, ali_prev, F_w, F_b, fout,
                     dec_prev, W_dec, b_enc, dec_ws);
  hipLaunchKernelGGL(k_score, dim3(512), dim3(512), 0, stream, enc, Wt2, fout, dec_ws, w_vec, enc_len, score);
  hipLaunchKernelGGL(k_softmax, dim3(32), dim3(256), 0, stream, score, enc_len, out);
  hipLaunchKernelGGL(k_ctx, dim3(1024), dim3(256), 0, stream, out, enc, enc_len, part);
  hipLaunchKernelGGL(k_ctx_red, dim3(128), dim3(256), 0, stream, part, out + 65536);
}

// Round 18
// 145.456 us; speedup vs baseline: 1.3100x; 1.0320x over previous
//
#include <hip/hip_runtime.h>

typedef __attribute__((ext_vector_type(4))) float f32x4;
typedef __attribute__((ext_vector_type(8))) short s16x8;
typedef __attribute__((ext_vector_type(8))) unsigned short u16x8;
typedef __attribute__((address_space(1))) unsigned int g_uint;
typedef __attribute__((address_space(3))) unsigned int lds_uint;

#define T_LEN 2048
#define ENC_D 1024
#define ATT_D 512
#define CONV_C 10

static __device__ __forceinline__ unsigned short f2bf(float f) {
  unsigned int u = __float_as_uint(f);
  u += 0x7FFFu + ((u >> 16) & 1u);
  return (unsigned short)(u >> 16);
}

static __device__ __forceinline__ void gload16(const void* g, void* l) {
  __builtin_amdgcn_global_load_lds((const g_uint*)g, (lds_uint*)l, 16, 0, 0);
}

// ---------------- K0: fused prep (Wt2 pack + W_att pack + conv129 + dec proj) --------------
// Blocks 0..127   : Wt2 tiles 0..15: tile(kt)[512 a][64 k] bf16, involution layout
//                   within-tile short offset: (a>>3)*512 + q*64 + ((a&7)^q)*8 + (k&7), q=(k>>3)&7
// Blocks 128..129 : tile 16 = W_att padded c->64, same layout
// Blocks 130..1409: f_out[n][c][t] = conv129(ali_prev) + F_b  (2 t per thread)
// Blocks 1410..1921: dec_ws[n][a] = dec_prev[n]@W_dec[:,a] + b_enc[a]
// All three are independent; fusing removes two launch bubbles. Branches are
// block-uniform so per-branch __syncthreads is legal.
__global__ void k_pre(const float* __restrict__ W, const float* __restrict__ Wa,
                      unsigned short* __restrict__ Wt2,
                      const float* __restrict__ ali, const float* __restrict__ Fw,
                      const float* __restrict__ Fb, float* __restrict__ fout,
                      const float* __restrict__ dec_prev, const float* __restrict__ Wd,
                      const float* __restrict__ benc, float* __restrict__ dec_ws) {
  __shared__ __align__(16) char sh[16640];
  int b = blockIdx.x;
  int tid = threadIdx.x;
  if (b < 128) {
    float (*tile)[65] = (float(*)[65])sh;     // 64 x 65 x 4 = 16640 B
    int kt = b & 15, ab = b >> 4;
    int k0 = kt * 64, a0 = ab * 64;
    int r = tid >> 2, cg = tid & 3;
    #pragma unroll
    for (int i = 0; i < 4; ++i) {
      f32x4 v = *reinterpret_cast<const f32x4*>(&W[(size_t)(k0 + r) * ATT_D + a0 + cg * 16 + i * 4]);
      tile[r][cg * 16 + i * 4 + 0] = v[0];
      tile[r][cg * 16 + i * 4 + 1] = v[1];
      tile[r][cg * 16 + i * 4 + 2] = v[2];
      tile[r][cg * 16 + i * 4 + 3] = v[3];
    }
    __syncthreads();
    int r2 = tid >> 2, kg = tid & 3;
    u16x8 o0, o1;
    #pragma unroll
    for (int j = 0; j < 8; ++j) o0[j] = f2bf(tile[kg * 16 + j][r2]);
    #pragma unroll
    for (int j = 0; j < 8; ++j) o1[j] = f2bf(tile[kg * 16 + 8 + j][r2]);
    int a = a0 + r2;            // 0..511
    int q0 = kg * 2, q1 = q0 + 1;
    size_t tb = (size_t)kt * 32768 + (a >> 3) * 512;
    int s7 = a & 7;
    *reinterpret_cast<u16x8*>(&Wt2[tb + q0 * 64 + (s7 ^ q0) * 8]) = o0;
    *reinterpret_cast<u16x8*>(&Wt2[tb + q1 * 64 + (s7 ^ q1) * 8]) = o1;
  } else if (b < 130) {
    int a = (b - 128) * 256 + tid;   // 0..511
    size_t tb = (size_t)16 * 32768 + (a >> 3) * 512;
    int s7 = a & 7;
    #pragma unroll
    for (int j = 0; j < 8; ++j) {
      u16x8 v;
      #pragma unroll
      for (int e = 0; e < 8; ++e) {
        int c = j * 8 + e;
        v[e] = (c < CONV_C) ? f2bf(Wa[a * CONV_C + c]) : (unsigned short)0;
      }
      *reinterpret_cast<u16x8*>(&Wt2[tb + j * 64 + (s7 ^ j) * 8]) = v;
    }
  } else if (b < 1410) {
    int bb = b - 130;               // 1280 = 32n x 10c x 4tb
    float* sa = (float*)sh;         // [640]
    float* sw = (float*)(sh + 2560);// [129]
    int tb = bb & 3, nc = bb >> 2;
    int c = nc % CONV_C, n = nc / CONV_C;
    int t0 = tb * 512;
    for (int i = tid; i < 640; i += 256) {
      int t = t0 - 64 + i;
      sa[i] = (t >= 0 && t < T_LEN) ? ali[n * T_LEN + t] : 0.f;
    }
    if (tid < 129) sw[tid] = Fw[c * 129 + tid];
    __syncthreads();
    float fb = Fb[c];
    float a0 = fb, a1 = fb;
    #pragma unroll 8
    for (int k = 0; k < 129; ++k) {
      float w = sw[k];
      a0 += w * sa[tid + k];
      a1 += w * sa[tid + 256 + k];
    }
    size_t base = (size_t)(n * CONV_C + c) * T_LEN + t0 + tid;
    fout[base] = a0;
    fout[base + 256] = a1;
  } else {
    int bb = b - 1410;              // 512 = 32n x 16ac
    float* red = (float*)sh;        // [256]
    int n = bb >> 4, ac = bb & 15;
    int dg = tid >> 5, al = tid & 31;
    int a = ac * 32 + al;
    const float* dp = dec_prev + (size_t)n * 1024 + dg * 128;
    const float* wp = Wd + (size_t)(dg * 128) * ATT_D + a;
    float s = 0.f;
    #pragma unroll 4
    for (int i = 0; i < 128; ++i) s += dp[i] * wp[(size_t)i * ATT_D];
    red[tid] = s;
    __syncthreads();
    if (dg == 0) {
      float t = benc[a];
      #pragma unroll
      for (int g = 0; g < 8; ++g) t += red[g * 32 + al];
      dec_ws[(size_t)n * ATT_D + a] = t;
    }
  }
}

// ---------------- K1: fused score GEMM (BM=128, BN=512, BK=64, 8 waves, 2-buffer) ----------
__global__ __launch_bounds__(512, 2) void k_score(
    const float* __restrict__ enc, const unsigned short* __restrict__ Wt2,
    const float* __restrict__ fout, const float* __restrict__ dec_ws,
    const float* __restrict__ w_vec, const int* __restrict__ enc_len,
    float* __restrict__ score_ws) {
  __shared__ __align__(16) char smem[163840];   // 2 x (B 65536 + A 16384)

  int bid = blockIdx.x;            // 512 blocks, paired mapping for balance
  int half = bid >> 8, p = bid & 255;
  int n = p >> 3, i0 = p & 7;
  int tt = half ? (15 - i0) : i0;
  int t0b = tt * 128;
  if (t0b >= enc_len[n]) return;   // fully-masked tile

  int tid = threadIdx.x;
  int w = tid >> 6, lane = tid & 63;
  int l15 = lane & 15, q = lane >> 4;
  int wm = w >> 2, wn = w & 3;     // 2(M) x 4(N); wave tile 64 x 128

  const float* Ab = enc + ((size_t)n * T_LEN + t0b) * ENC_D;
  int arow = tid >> 2, aq4 = tid & 3;          // A row 0..127, 16-f32 span
  const float* Asrc = Ab + (size_t)arow * ENC_D + aq4 * 16;
  int c0 = aq4 * 2, c1 = c0 + 1;
  int awoff0 = 65536 + (arow >> 3) * 1024 + c0 * 128 + ((arow & 7) ^ c0) * 16;
  int awoff1 = 65536 + (arow >> 3) * 1024 + c1 * 128 + ((arow & 7) ^ c1) * 16;

  // fragment-read offsets (bytes)
  int x0 = (l15 & 7) ^ q;
  int ck0 = q * 128 + x0 * 16;                 // kk=0 chunk q
  int ck1 = 512 + q * 128 + (x0 ^ 4) * 16;     // kk=1 chunk 4+q
  int rgA = wm * 8 + (l15 >> 3);
  int rgB = wn * 16 + (l15 >> 3);

  char* b0 = smem;
  char* b1 = smem + 81920;

  f32x4 acc[4][8];
  #pragma unroll
  for (int m = 0; m < 4; ++m)
    #pragma unroll
    for (int nf = 0; nf < 8; ++nf)
      acc[m][nf] = (f32x4){0.f, 0.f, 0.f, 0.f};

  f32x4 xA0, xA1, xA2, xA3;

  auto STAGE = [&](int kt, char* buf) {
    const float* pA = Asrc + (size_t)kt * 64;
    xA0 = *reinterpret_cast<const f32x4*>(pA);
    xA1 = *reinterpret_cast<const f32x4*>(pA + 4);
    xA2 = *reinterpret_cast<const f32x4*>(pA + 8);
    xA3 = *reinterpret_cast<const f32x4*>(pA + 12);
    const unsigned short* s = Wt2 + (size_t)kt * 32768 + tid * 8;
    #pragma unroll
    for (int i = 0; i < 8; ++i)
      gload16(s + i * 4096, buf + tid * 16 + i * 8192);
  };
  auto WRITEA = [&](char* buf) {
    union { u16x8 v; unsigned int u[4]; } p0, p1;
    asm("v_cvt_pk_bf16_f32 %0, %1, %2" : "=v"(p0.u[0]) : "v"(xA0[0]), "v"(xA0[1]));
    asm("v_cvt_pk_bf16_f32 %0, %1, %2" : "=v"(p0.u[1]) : "v"(xA0[2]), "v"(xA0[3]));
    asm("v_cvt_pk_bf16_f32 %0, %1, %2" : "=v"(p0.u[2]) : "v"(xA1[0]), "v"(xA1[1]));
    asm("v_cvt_pk_bf16_f32 %0, %1, %2" : "=v"(p0.u[3]) : "v"(xA1[2]), "v"(xA1[3]));
    asm("v_cvt_pk_bf16_f32 %0, %1, %2" : "=v"(p1.u[0]) : "v"(xA2[0]), "v"(xA2[1]));
    asm("v_cvt_pk_bf16_f32 %0, %1, %2" : "=v"(p1.u[1]) : "v"(xA2[2]), "v"(xA2[3]));
    asm("v_cvt_pk_bf16_f32 %0, %1, %2" : "=v"(p1.u[2]) : "v"(xA3[0]), "v"(xA3[1]));
    asm("v_cvt_pk_bf16_f32 %0, %1, %2" : "=v"(p1.u[3]) : "v"(xA3[2]), "v"(xA3[3]));
    *reinterpret_cast<u16x8*>(buf + awoff0) = p0.v;
    *reinterpret_cast<u16x8*>(buf + awoff1) = p1.v;
  };
  auto compute = [&](const char* buf) {
    s16x8 af0[4], af1[4];
    #pragma unroll
    for (int m = 0; m < 4; ++m) {
      af0[m] = *reinterpret_cast<const s16x8*>(buf + 65536 + (rgA + m * 2) * 1024 + ck0);
      af1[m] = *reinterpret_cast<const s16x8*>(buf + 65536 + (rgA + m * 2) * 1024 + ck1);
    }
    __builtin_amdgcn_s_setprio(1);
    #pragma unroll
    for (int nf = 0; nf < 8; ++nf) {
      s16x8 bf0 = *reinterpret_cast<const s16x8*>(buf + (rgB + nf * 2) * 1024 + ck0);
      s16x8 bf1 = *reinterpret_cast<const s16x8*>(buf + (rgB + nf * 2) * 1024 + ck1);
      #pragma unroll
      for (int m = 0; m < 4; ++m) {
        acc[m][nf] = __builtin_amdgcn_mfma_f32_16x16x32_bf16(af0[m], bf0, acc[m][nf], 0, 0, 0);
        acc[m][nf] = __builtin_amdgcn_mfma_f32_16x16x32_bf16(af1[m], bf1, acc[m][nf], 0, 0, 0);
      }
    }
    __builtin_amdgcn_s_setprio(0);
  };

  // ---- prologue: att tile (f-values + W_att) into b0, k=0 into b1 ----
  if (tid < 128) {                 // f tile: [128 t][64 c] bf16, c >= 10 zero
    float fv[CONV_C];
    #pragma unroll
    for (int c = 0; c < CONV_C; ++c)
      fv[c] = fout[((size_t)n * CONV_C + c) * T_LEN + t0b + tid];
    char* base = b0 + 65536 + (tid >> 3) * 1024;
    int s7 = tid & 7;
    #pragma unroll
    for (int j = 0; j < 8; ++j) {
      u16x8 v;
      #pragma unroll
      for (int e = 0; e < 8; ++e) {
        int c = j * 8 + e;
        v[e] = (c < CONV_C) ? f2bf(fv[c]) : (unsigned short)0;
      }
      *reinterpret_cast<u16x8*>(base + j * 128 + (s7 ^ j) * 16) = v;
    }
  }
  {
    const unsigned short* s = Wt2 + (size_t)16 * 32768 + tid * 8;
    #pragma unroll
    for (int i = 0; i < 8; ++i)
      gload16(s + i * 4096, b0 + tid * 16 + i * 8192);
  }
  STAGE(0, b1);
  asm volatile("s_waitcnt vmcnt(0) lgkmcnt(0)" ::: "memory");
  __builtin_amdgcn_sched_barrier(0);
  __builtin_amdgcn_s_barrier();
  compute(b0);                     // att_part
  WRITEA(b1);                      // A(0)

  char* pc = b1; char* pn = b0;
  for (int k = 0; k < 16; ++k) {
    asm volatile("s_waitcnt vmcnt(0) lgkmcnt(0)" ::: "memory");
    __builtin_amdgcn_sched_barrier(0);
    __builtin_amdgcn_s_barrier();
    if (k + 1 < 16) STAGE(k + 1, pn);
    compute(pc);
    if (k + 1 < 16) WRITEA(pn);
    char* t = pc; pc = pn; pn = t;
  }
  __syncthreads();

  // ---- epilogue: + dec, tanh, dot(w), row-reduce ----
  float* d_lds = (float*)smem;               // [512]
  float* w_lds = (float*)(smem + 2048);      // [512]
  float* red   = (float*)(smem + 4096);      // [4][128]
  d_lds[tid] = dec_ws[(size_t)n * ATT_D + tid];
  w_lds[tid] = w_vec[tid];
  __syncthreads();

  #pragma unroll
  for (int m = 0; m < 4; ++m) {
    #pragma unroll
    for (int j = 0; j < 4; ++j) {
      int ttl = wm * 64 + m * 16 + q * 4 + j;
      float s = 0.f;
      #pragma unroll
      for (int nf = 0; nf < 8; ++nf) {
        int cl = wn * 128 + nf * 16 + l15;
        float x = acc[m][nf][j] + d_lds[cl];
        float e = __expf(2.f * x);
        float th = 1.f - 2.f / (e + 1.f);
        s += w_lds[cl] * th;
      }
      float v = s;
      v += __shfl_xor(v, 1);
      v += __shfl_xor(v, 2);
      v += __shfl_xor(v, 4);
      v += __shfl_xor(v, 8);
      if (l15 == 0) red[wn * 128 + ttl] = v;
    }
  }
  __syncthreads();
  if (tid < 128) {
    float s = red[tid] + red[128 + tid] + red[256 + tid] + red[384 + tid];
    score_ws[(size_t)n * T_LEN + t0b + tid] = s;
  }
}

// ---------------- K2: masked softmax over T per row ----------------
__global__ void k_softmax(const float* __restrict__ score_ws, const int* __restrict__ enc_len,
                          float* __restrict__ ali_out) {
  __shared__ float wmx[4], wsum[4];
  int n = blockIdx.x, tid = threadIdx.x;
  int len = enc_len[n];
  int w = tid >> 6, lane = tid & 63;
  float s[8], e[8];
  float mx = -1e30f;
  #pragma unroll
  for (int i = 0; i < 8; ++i) {
    int t = i * 256 + tid;
    float v = score_ws[n * T_LEN + t];
    s[i] = v;
    if (t < len) mx = fmaxf(mx, v);
  }
  #pragma unroll
  for (int off = 32; off; off >>= 1) mx = fmaxf(mx, __shfl_xor(mx, off));
  if (lane == 0) wmx[w] = mx;
  __syncthreads();
  mx = fmaxf(fmaxf(wmx[0], wmx[1]), fmaxf(wmx[2], wmx[3]));
  float sum = 0.f;
  #pragma unroll
  for (int i = 0; i < 8; ++i) {
    int t = i * 256 + tid;
    float v = (t < len) ? __expf(s[i] - mx) : 0.f;
    e[i] = v;
    sum += v;
  }
  #pragma unroll
  for (int off = 32; off; off >>= 1) sum += __shfl_xor(sum, off);
  if (lane == 0) wsum[w] = sum;
  __syncthreads();
  sum = wsum[0] + wsum[1] + wsum[2] + wsum[3];
  float inv = 1.f / sum;
  #pragma unroll
  for (int i = 0; i < 8; ++i) ali_out[n * T_LEN + i * 256 + tid] = e[i] * inv;
}

// ---------------- K3: ctx partials over T-chunks (skip masked chunks) ----------------
__global__ void k_ctx(const float* __restrict__ ali, const float* __restrict__ enc,
                      const int* __restrict__ enc_len, float* __restrict__ part) {
  int b = blockIdx.x;                   // n*32 + tc
  int n = b >> 5, tc = b & 31;
  int tid = threadIdx.x;
  if (tc * 64 >= enc_len[n]) {
    *reinterpret_cast<f32x4*>(&part[(size_t)b * ENC_D + tid * 4]) = (f32x4){0.f, 0.f, 0.f, 0.f};
    return;
  }
  f32x4 acc = (f32x4){0.f, 0.f, 0.f, 0.f};
  const float* ep = enc + (size_t)(n * T_LEN + tc * 64) * ENC_D + tid * 4;
  const float* ap = ali + n * T_LEN + tc * 64;
  #pragma unroll 4
  for (int i = 0; i < 64; ++i) {
    float a = ap[i];
    f32x4 ev = *reinterpret_cast<const f32x4*>(ep + (size_t)i * ENC_D);
    acc += ev * a;
  }
  *reinterpret_cast<f32x4*>(&part[(size_t)b * ENC_D + tid * 4]) = acc;
}

// ---------------- K4: reduce ctx partials ----------------
__global__ void k_ctx_red(const float* __restrict__ part, float* __restrict__ ctx_out) {
  int g = blockIdx.x * 256 + threadIdx.x;
  int n = g >> 10, d = g & 1023;
  float s = 0.f;
  #pragma unroll 8
  for (int tc = 0; tc < 32; ++tc) s += part[(size_t)(n * 32 + tc) * ENC_D + d];
  ctx_out[g] = s;
}

extern "C" void kernel_launch(void* const* d_in, const int* in_sizes, int n_in,
                              void* d_out, int out_size, void* d_ws, size_t ws_size,
                              hipStream_t stream) {
  const float* enc      = (const float*)d_in[0];
  const int*   enc_len  = (const int*)d_in[1];
  const float* dec_prev = (const float*)d_in[2];
  const float* ali_prev = (const float*)d_in[3];
  const float* W_enc    = (const float*)d_in[4];
  const float* b_enc    = (const float*)d_in[5];
  const float* W_dec    = (const float*)d_in[6];
  const float* F_w      = (const float*)d_in[7];
  const float* F_b      = (const float*)d_in[8];
  const float* W_att    = (const float*)d_in[9];
  const float* w_vec    = (const float*)d_in[10];
  float* out = (float*)d_out;

  char* ws = (char*)d_ws;
  unsigned short* Wt2 = (unsigned short*)ws;       // 17 x 65536 B = 1,114,112
  float* fout   = (float*)(ws + 1114112);          // 2,621,440 B
  float* dec_ws = (float*)(ws + 3735552);          //    65,536 B
  float* score  = (float*)(ws + 3801088);          //   262,144 B
  float* part   = (float*)(ws + 4063232);          // 4,194,304 B

  hipLaunchKernelGGL(k_pre, dim3(1922), dim3(256), 0, stream,
                     W_enc, W_att, Wt2, ali_prev, F_w, F_b, fout,
                     dec_prev, W_dec, b_enc, dec_ws);
  hipLaunchKernelGGL(k_score, dim3(512), dim3(512), 0, stream, enc, Wt2, fout, dec_ws, w_vec, enc_len, score);
  hipLaunchKernelGGL(k_softmax, dim3(32), dim3(256), 0, stream, score, enc_len, out);
  hipLaunchKernelGGL(k_ctx, dim3(1024), dim3(256), 0, stream, out, enc, enc_len, part);
  hipLaunchKernelGGL(k_ctx_red, dim3(128), dim3(256), 0, stream, part, out + 65536);
}